// Round 6
// baseline (649.442 us; speedup 1.0000x reference)
//
#include <hip/hip_runtime.h>

typedef unsigned short u16;
typedef u16 u16x8 __attribute__((ext_vector_type(8)));
typedef u16 u16x4 __attribute__((ext_vector_type(4)));
typedef __bf16 bf16x8 __attribute__((ext_vector_type(8)));
typedef float f32x4 __attribute__((ext_vector_type(4)));

#define DEVI static __device__ __forceinline__

DEVI float b2f(u16 u){ union { unsigned u; float f; } c; c.u = ((unsigned)u) << 16; return c.f; }
DEVI u16 f2b(float f){ union { float f; unsigned u; } c; c.f = f;
  unsigned r = c.u + 0x7fffu + ((c.u >> 16) & 1u); return (u16)(r >> 16); }
DEVI void gload16(const void* g, void* l){
  __builtin_amdgcn_global_load_lds((const __attribute__((address_space(1))) void*)g,
                                   (__attribute__((address_space(3))) void*)l, 16, 0, 0);
}
DEVI f32x4 MFMA(bf16x8 a, bf16x8 b, f32x4 c){
  return __builtin_amdgcn_mfma_f32_16x16x32_bf16(a, b, c, 0, 0, 0);
}
#define WAITV(n) asm volatile("s_waitcnt vmcnt(" #n ")" ::: "memory")
#define BAR()    do { __builtin_amdgcn_s_barrier(); asm volatile("" ::: "memory"); } while(0)

// B=2, L=2048, HID=2048, H=16, HKV=8, D=128, CHUNK=64, NC=32, TOK=4096
constexpr size_t OFF_HB  = 0;                                   // h bf16 [4096][2048]
constexpr size_t OFF_WCT = OFF_HB  + (size_t)4096*2048*2;       // WcatT bf16 (Wq|Wk|Wv)^T [4096][2048]
constexpr size_t OFF_WOT = OFF_WCT + (size_t)4224*2048*2;       // WoT bf16 [2048][2048]
constexpr size_t OFF_QKV = OFF_WOT + (size_t)2048*2048*2;       // QKV bf16 [4096][4096]
constexpr size_t OFF_G1  = OFF_QKV + (size_t)4096*4096*2;       // (unused)
constexpr size_t OFF_G   = OFF_G1  + (size_t)4096*16*4;         // g f32 [4096][1024]
constexpr size_t OFF_EB  = OFF_G   + (size_t)4096*1024*4;       // exp(b) bf16 [4096][1024]
constexpr size_t OFF_KD  = OFF_EB  + (size_t)4096*1024*2;       // k*exp(-b) bf16 [4096][1024]
constexpr size_t OFF_T   = OFF_KD  + (size_t)4096*1024*2;       // T bf16 [2][8][32][128][128]; wtilT overlays pre-phaseA
constexpr size_t OFF_DV  = OFF_T   + (size_t)2*8*32*128*128*2;  // Dvec f32 [2][8][32][128]
constexpr size_t OFF_SP  = OFF_DV  + (size_t)2*8*32*128*4;      // S_prefix bf16 [2][8][32][128][128]
constexpr size_t OFF_ON  = OFF_SP  + (size_t)2*8*32*128*128*2;  // o_normed bf16 [4096][2048]

// ---------------- conversion ----------------
__global__ __launch_bounds__(256) void k_conv_h(const float* __restrict__ h, u16* __restrict__ hb){
  int idx = blockIdx.x*256 + threadIdx.x, stride = gridDim.x*256;
  for (int i = idx; i < 4096*2048/4; i += stride){
    float4 v = ((const float4*)h)[i];
    u16x4 o; o[0]=f2b(v.x); o[1]=f2b(v.y); o[2]=f2b(v.z); o[3]=f2b(v.w);
    ((u16x4*)hb)[i] = o;
  }
}

// dst[(rowOff+n)*pitch + k] = bf16(src[k][n])
__global__ __launch_bounds__(256) void k_transpose(const float* __restrict__ src, u16* __restrict__ dst,
                                                   int K, int N, int rowOff, int pitch){
  __shared__ float tile[64][65];
  int kb = blockIdx.y*64, nb = blockIdx.x*64;
  int t = threadIdx.x, x = t & 63, y0 = t >> 6;
#pragma unroll
  for (int i = 0; i < 16; i++){
    int y = y0 + i*4, k = kb + y, n = nb + x;
    tile[y][x] = (n < N) ? src[(size_t)k*N + n] : 0.f;
  }
  __syncthreads();
#pragma unroll
  for (int i = 0; i < 16; i++){
    int y = y0 + i*4, n = nb + y, k = kb + x;
    if (n < N) dst[(size_t)(rowOff + n)*pitch + k] = f2b(tile[x][y]);
  }
}

// ---------------- wtilT[c][r] = bf16( sum_j Wg1[r][j] * Wg2[j][c] ) ----------------
__global__ __launch_bounds__(256) void k_wtilde(const float* __restrict__ Wg1, const float* __restrict__ Wg2,
                                                u16* __restrict__ wt){
  int c = blockIdx.x, t = threadIdx.x;
  float w2[16];
#pragma unroll
  for (int j = 0; j < 16; j++) w2[j] = Wg2[j*1024 + c];
  int r0 = t*8;
  u16x8 o;
#pragma unroll
  for (int u = 0; u < 8; u++){
    const float* row = Wg1 + (size_t)(r0+u)*16;
    float s = 0.f;
#pragma unroll
    for (int j = 0; j < 16; j++) s += row[j]*w2[j];
    o[u] = f2b(s);
  }
  *(u16x8*)&wt[(size_t)c*2048 + r0] = o;
}

// ---------------- 8-phase pipelined GEMM (m201-style) ----------------
// C[m][n] = sum_k A[m][k]*Bt[n][k], K=2048, BK=64, BN=256, 8 waves (2x4), wave tile (BM/2)x64.
// LDS: 2 slots; A: [row][8 granules] swizzled g^=row&7 ; B: [kk][row][4 granules] swizzled j^=(row>>1)&3.
// Per K-tile: 4 phases (kk,mhalf); counted vmcnt(4) mid-tile, vmcnt(2) at boundary, each + barrier.
// MODE 0: QKV+gate epilogue (N=5120). MODE 1: fp32 store (N=2048).
template<int BM, int MODE>
__global__ __launch_bounds__(512, 2) void gemm8p(const u16* __restrict__ A,
                                                 const u16* __restrict__ BtLo,
                                                 const u16* __restrict__ BtHi,
                                                 u16* __restrict__ Cq, float* __restrict__ Cg,
                                                 float* __restrict__ Cf,
                                                 const float* __restrict__ bq,
                                                 const float* __restrict__ bk,
                                                 const float* __restrict__ bv,
                                                 const float* __restrict__ bg2){
  constexpr int K = 2048, NT = 32;
  constexpr int FH = BM/64;        // A frags per m-half
  constexpr int MI = BM/32;        // total m frags per wave
  constexpr int AL = BM*8/512;     // A gloads per K-tile per thread
  constexpr int NTN = (MODE==0) ? 20 : 8;
  constexpr int CPX = (MODE==0) ? 40 : 32;
  __shared__ u16 sA[2*BM*64];
  __shared__ u16 sB[2*256*64];
  int id = blockIdx.x;
  int swz = (id & 7)*CPX + (id >> 3);
  int mt = swz / NTN, nt = swz % NTN;
  int t = threadIdx.x, w = t >> 6, l = t & 63;
  int wr = w >> 2, wc = w & 3;
  int mRow0 = mt*BM, nCol0 = nt*256;
  const u16* Bbase = (MODE==0 && nCol0 >= 4096) ? (BtHi + (size_t)(nCol0-4096)*K)
                                                : (BtLo + (size_t)nCol0*K);
  const u16* srcA[AL];
#pragma unroll
  for (int i = 0; i < AL; i++){
    int G = i*512 + t, row = G>>3, g = (G&7) ^ (row&7);
    srcA[i] = A + (size_t)(mRow0+row)*K + g*8;
  }
  const u16* srcB[2][2];
#pragma unroll
  for (int kk = 0; kk < 2; kk++)
#pragma unroll
    for (int i = 0; i < 2; i++){
      int S = i*512 + t, row = S>>2, j = (S&3) ^ ((row>>1)&3);
      srcB[kk][i] = Bbase + (size_t)row*K + kk*32 + j*8;
    }
  auto stA = [&](int T1, int i){
    u16* d = sA + (T1&1)*(BM*64) + (size_t)(i*512 + w*64)*8;
    gload16(srcA[i] + T1*64, d);
  };
  auto stB = [&](int T1, int kk, int i){
    u16* d = sB + (T1&1)*(256*64) + kk*8192 + (size_t)(i*512 + w*64)*8;
    gload16(srcB[kk][i] + T1*64, d);
  };
  bf16x8 af[FH], bfr[4];
  auto rdA = [&](int slot, int mh, int kk){
    const u16* base = sA + slot*(BM*64);
#pragma unroll
    for (int f = 0; f < FH; f++){
      int row = wr*(BM/2) + mh*(BM/4) + f*16 + (l&15);
      int gr = (kk*4 + (l>>4)) ^ (row&7);
      af[f] = *(const bf16x8*)&base[row*64 + gr*8];
    }
  };
  auto rdB = [&](int slot, int kk){
    const u16* base = sB + slot*(256*64) + kk*8192;
#pragma unroll
    for (int n = 0; n < 4; n++){
      int row = wc*64 + n*16 + (l&15);
      int jr = (l>>4) ^ ((row>>1)&3);
      bfr[n] = *(const bf16x8*)&base[row*32 + jr*8];
    }
  };
  f32x4 acc[MI][4] = {};
  auto mm = [&](int mh){
    __builtin_amdgcn_s_setprio(1);
#pragma unroll
    for (int f = 0; f < FH; f++)
#pragma unroll
      for (int n = 0; n < 4; n++)
        acc[mh*FH+f][n] = MFMA(af[f], bfr[n], acc[mh*FH+f][n]);
    __builtin_amdgcn_s_setprio(0);
  };
  // prologue: stage tile 0 (order: A, Bk0, Bk1)
#pragma unroll
  for (int i = 0; i < AL; i++) stA(0, i);
  stB(0,0,0); stB(0,0,1); stB(0,1,0); stB(0,1,1);
  WAITV(2);
  BAR();
  for (int T = 0; T < NT; ++T){
    int slot = T & 1;
    bool pf = (T+1 < NT);
    // phase 0: (kk0, m-half 0)
    rdA(slot, 0, 0); rdB(slot, 0);
    if (pf){ stA(T+1,0); stA(T+1,1); }
    BAR();
    mm(0);
    BAR();
    // phase 1: (kk0, m-half 1)
    rdA(slot, 1, 0);
    if (pf){ if constexpr (BM==256){ stA(T+1,2); stA(T+1,3); } else { stB(T+1,0,0); stB(T+1,0,1); } }
    BAR();
    mm(1);
    if (pf) WAITV(4); else WAITV(0);
    BAR();
    // phase 2: (kk1, m-half 0)
    rdA(slot, 0, 1); rdB(slot, 1);
    if (pf){ if constexpr (BM==256){ stB(T+1,0,0); stB(T+1,0,1); } else { stB(T+1,1,0); stB(T+1,1,1); } }
    BAR();
    mm(0);
    BAR();
    // phase 3: (kk1, m-half 1)
    rdA(slot, 1, 1);
    if (pf){ if constexpr (BM==256){ stB(T+1,1,0); stB(T+1,1,1); } }
    BAR();
    mm(1);
    if (pf) WAITV(2);
    BAR();
  }
  // epilogue
  int iLoc = (l>>4)*4, jc = l & 15;
  if (MODE == 0){
#pragma unroll
    for (int ni = 0; ni < 4; ni++){
      int n0 = nCol0 + wc*64 + ni*16;
      int n = n0 + jc;
      int kind; float bias;
      if (n0 < 2048){ kind = 0; bias = bq[n]; }
      else if (n0 < 3072){ kind = 1; bias = bk[n - 2048]; }
      else if (n0 < 4096){ kind = 2; bias = bv[n - 3072]; }
      else { kind = 3; bias = bg2[n - 4096]; }
#pragma unroll
      for (int mi = 0; mi < MI; mi++){
        int m = mRow0 + wr*(BM/2) + (mi/FH)*(BM/4) + (mi%FH)*16 + iLoc;
#pragma unroll
        for (int rr = 0; rr < 4; rr++){
          float x = acc[mi][ni][rr] + bias;
          int row = m + rr;
          if (kind == 0)      Cq[(size_t)row*4096 + n] = f2b(fmaxf(x, 0.f) * 0.08838834764831845f);
          else if (kind == 1) Cq[(size_t)row*4096 + n] = f2b(fmaxf(x, 0.f));
          else if (kind == 2) Cq[(size_t)row*4096 + n] = f2b(x);
          else Cg[(size_t)row*1024 + (n - 4096)] = (fminf(x,0.f) - log1pf(expf(-fabsf(x)))) * 0.0625f;
        }
      }
    }
  } else {
#pragma unroll
    for (int ni = 0; ni < 4; ni++){
      int n = nCol0 + wc*64 + ni*16 + jc;
#pragma unroll
      for (int mi = 0; mi < MI; mi++){
        int m = mRow0 + wr*(BM/2) + (mi/FH)*(BM/4) + (mi%FH)*16 + iLoc;
#pragma unroll
        for (int rr = 0; rr < 4; rr++) Cf[(size_t)(m+rr)*2048 + n] = acc[mi][ni][rr];
      }
    }
  }
}

// ---------------- phase A ----------------
__global__ __launch_bounds__(256) void k_phaseA(const float* __restrict__ g, const u16* __restrict__ QKV,
                                                u16* __restrict__ eb, u16* __restrict__ kd,
                                                u16* __restrict__ T, float* __restrict__ Dv){
  __shared__ float gb[64*128];
  __shared__ u16 keT[128*72];
  __shared__ u16 vT [128*72];
  int c = blockIdx.x, kvh = blockIdx.y, b = blockIdx.z;
  int t = threadIdx.x;
  int tok0 = b*2048 + c*64;
#pragma unroll
  for (int r = 0; r < 8; r++){
    int idx4 = r*256 + t;
    int i = idx4 >> 5, c4 = idx4 & 31;
    ((float4*)gb)[i*32 + c4] = *(const float4*)&g[(size_t)(tok0+i)*1024 + kvh*128 + c4*4];
  }
  __syncthreads();
  if (t < 128){
    float run = 0.f;
    for (int i = 0; i < 64; i++){ run += gb[i*128 + t]; gb[i*128 + t] = run; }
    Dv[((size_t)(b*8+kvh)*32 + c)*128 + t] = expf(run);
  }
  __syncthreads();
  int d0 = (t&15)*8;
  float blast[8];
#pragma unroll
  for (int j = 0; j < 8; j++) blast[j] = gb[63*128 + d0 + j];
#pragma unroll
  for (int r = 0; r < 4; r++){
    int i = (t>>4) + r*16;
    u16x8 kv_ = *(const u16x8*)&QKV[(size_t)(tok0+i)*4096 + 2048 + kvh*128 + d0];
    u16x8 vv  = *(const u16x8*)&QKV[(size_t)(tok0+i)*4096 + 3072 + kvh*128 + d0];
    u16x8 ebv, kdv;
#pragma unroll
    for (int j = 0; j < 8; j++){
      float bcur = gb[i*128 + d0 + j];
      float kf = b2f(kv_[j]);
      ebv[j] = f2b(expf(bcur));
      kdv[j] = f2b(kf * expf(-bcur));
      keT[(d0+j)*72 + i] = f2b(kf * expf(blast[j] - bcur));
      vT [(d0+j)*72 + i] = vv[j];
    }
    *(u16x8*)&eb[(size_t)(tok0+i)*1024 + kvh*128 + d0] = ebv;
    *(u16x8*)&kd[(size_t)(tok0+i)*1024 + kvh*128 + d0] = kdv;
  }
  __syncthreads();
  int w = t>>6, l = t&63;
  f32x4 acc[2][8] = {};
#pragma unroll
  for (int ks = 0; ks < 2; ks++){
    bf16x8 af[2];
#pragma unroll
    for (int ti = 0; ti < 2; ti++)
      af[ti] = *(const bf16x8*)&keT[(w*32 + ti*16 + (l&15))*72 + ks*32 + (l>>4)*8];
#pragma unroll
    for (int tj = 0; tj < 8; tj++){
      bf16x8 bf_ = *(const bf16x8*)&vT[(tj*16 + (l&15))*72 + ks*32 + (l>>4)*8];
#pragma unroll
      for (int ti = 0; ti < 2; ti++) acc[ti][tj] = MFMA(af[ti], bf_, acc[ti][tj]);
    }
  }
  size_t tbase = ((size_t)(b*8+kvh)*32 + c)*16384;
#pragma unroll
  for (int ti = 0; ti < 2; ti++)
#pragma unroll
    for (int tj = 0; tj < 8; tj++)
#pragma unroll
      for (int rr = 0; rr < 4; rr++){
        int d = w*32 + ti*16 + (l>>4)*4 + rr, e = tj*16 + (l&15);
        T[tbase + d*128 + e] = f2b(acc[ti][tj][rr]);
      }
}

// ---------------- phase B ----------------
__global__ __launch_bounds__(256) void k_phaseB(const u16* __restrict__ T, const float* __restrict__ Dv,
                                                u16* __restrict__ SP){
  __shared__ u16 sl[16*128];
  int es = blockIdx.x, kvh = blockIdx.y, b = blockIdx.z;
  int t = threadIdx.x;
  size_t bh = (size_t)(b*8 + kvh);
  float S[8] = {0,0,0,0,0,0,0,0};
  for (int c = 0; c < 32; c++){
#pragma unroll
    for (int r = 0; r < 8; r++){
      int idx = r*256 + t, d = idx>>4, el = idx&15;
      sl[el*128 + d] = f2b(S[r]);
    }
    __syncthreads();
    size_t spb = (bh*32 + c)*16384 + (size_t)es*2048;
    *(u16x8*)&SP[spb + t*8] = *(const u16x8*)&sl[t*8];
    size_t tb  = (bh*32 + c)*16384;
    size_t dvb = (bh*32 + c)*128;
#pragma unroll
    for (int r = 0; r < 8; r++){
      int idx = r*256 + t, d = idx>>4, el = idx&15;
      float tv = b2f(T[tb + d*128 + es*16 + el]);
      S[r] = S[r]*Dv[dvb + d] + tv;
    }
    __syncthreads();
  }
}

// ---------------- phase C ----------------
__global__ __launch_bounds__(256) void k_phaseC(const u16* __restrict__ QKV, const u16* __restrict__ eb,
                                                const u16* __restrict__ kd, const u16* __restrict__ SP,
                                                const float* __restrict__ gnw, u16* __restrict__ onrm){
  __shared__ u16 kl[64*128];
  __shared__ u16 sl[64*72];
  __shared__ u16 vT[128*72];
  int c = blockIdx.x, h = blockIdx.y, b = blockIdx.z;
  int kvh = h >> 1;
  int t = threadIdx.x, w = t>>6, l = t&63;
  int tok0 = b*2048 + c*64;
#pragma unroll
  for (int is = 0; is < 4; is++){
    int row = (t>>4) + is*16;
    int d0s = 8*((t&15) ^ (row&7));
    gload16(&kd[(size_t)(tok0+row)*1024 + kvh*128 + d0s], &kl[is*2048 + w*512]);
  }
  int d0v = (t&15)*8;
#pragma unroll
  for (int r = 0; r < 4; r++){
    int i = (t>>4) + r*16;
    u16x8 vv = *(const u16x8*)&QKV[(size_t)(tok0+i)*4096 + 3072 + kvh*128 + d0v];
#pragma unroll
    for (int jj = 0; jj < 8; jj++) vT[(d0v+jj)*72 + i] = vv[jj];
  }
  bf16x8 aq[4];
  {
    int i = w*16 + (l&15);
#pragma unroll
    for (int kt = 0; kt < 4; kt++){
      int dq = kt*32 + (l>>4)*8;
      u16x8 qv = *(const u16x8*)&QKV[(size_t)(tok0+i)*4096 + h*128 + dq];
      u16x8 ev = *(const u16x8*)&eb[(size_t)(tok0+i)*1024 + kvh*128 + dq];
      u16x8 o;
#pragma unroll
      for (int jj = 0; jj < 8; jj++) o[jj] = f2b(b2f(qv[jj]) * b2f(ev[jj]));
      aq[kt] = __builtin_bit_cast(bf16x8, o);
    }
  }
  __syncthreads();
  f32x4 accs[4] = {};
#pragma unroll
  for (int kt = 0; kt < 4; kt++){
#pragma unroll
    for (int jt = 0; jt < 4; jt++){
      int j = jt*16 + (l&15);
      int byte_ = j*256 + ((2*(kt*32 + (l>>4)*8)) ^ ((j&7)<<4));
      bf16x8 bk_ = *(const bf16x8*)((const char*)kl + byte_);
      accs[jt] = MFMA(aq[kt], bk_, accs[jt]);
    }
  }
#pragma unroll
  for (int jt = 0; jt < 4; jt++)
#pragma unroll
    for (int rr = 0; rr < 4; rr++){
      int i = w*16 + (l>>4)*4 + rr;
      int j = jt*16 + (l&15);
      sl[i*72 + j] = f2b((i >= j) ? accs[jt][rr] : 0.f);
    }
  f32x4 acco[8] = {};
  size_t spb = ((size_t)(b*8+kvh)*32 + c)*16384;
#pragma unroll
  for (int kt = 0; kt < 4; kt++){
#pragma unroll
    for (int et = 0; et < 8; et++){
      int e = et*16 + (l&15);
      int dd = kt*32 + (l>>4)*8;
      bf16x8 bs = *(const bf16x8*)&SP[spb + (size_t)e*128 + dd];
      acco[et] = MFMA(aq[kt], bs, acco[et]);
    }
  }
#pragma unroll
  for (int kt2 = 0; kt2 < 2; kt2++){
    int i = w*16 + (l&15);
    bf16x8 as = *(const bf16x8*)&sl[i*72 + kt2*32 + (l>>4)*8];
#pragma unroll
    for (int et = 0; et < 8; et++){
      bf16x8 bv_ = *(const bf16x8*)&vT[(et*16 + (l&15))*72 + kt2*32 + (l>>4)*8];
      acco[et] = MFMA(as, bv_, acco[et]);
    }
  }
  float gw[8];
#pragma unroll
  for (int et = 0; et < 8; et++) gw[et] = gnw[et*16 + (l&15)];
#pragma unroll
  for (int rr = 0; rr < 4; rr++){
    int i = w*16 + (l>>4)*4 + rr;
    float ss = 0.f;
#pragma unroll
    for (int et = 0; et < 8; et++){ float x = acco[et][rr]; ss += x*x; }
    ss += __shfl_xor(ss, 1); ss += __shfl_xor(ss, 2);
    ss += __shfl_xor(ss, 4); ss += __shfl_xor(ss, 8);
    float sc = rsqrtf(ss*(1.f/128.f) + 1e-5f);
#pragma unroll
    for (int et = 0; et < 8; et++){
      int e = et*16 + (l&15);
      onrm[(size_t)(tok0+i)*2048 + h*128 + e] = f2b(acco[et][rr]*sc*gw[et]);
    }
  }
}

extern "C" void kernel_launch(void* const* d_in, const int* in_sizes, int n_in,
                              void* d_out, int out_size, void* d_ws, size_t ws_size,
                              hipStream_t stream){
  (void)in_sizes; (void)n_in; (void)out_size; (void)ws_size;
  const float* h   = (const float*)d_in[0];
  const float* Wq  = (const float*)d_in[1];
  const float* bq  = (const float*)d_in[2];
  const float* Wk  = (const float*)d_in[3];
  const float* bk  = (const float*)d_in[4];
  const float* Wv  = (const float*)d_in[5];
  const float* bv  = (const float*)d_in[6];
  const float* Wg1 = (const float*)d_in[7];
  const float* Wg2 = (const float*)d_in[8];
  const float* bg2 = (const float*)d_in[9];
  const float* gnw = (const float*)d_in[10];
  const float* Wo  = (const float*)d_in[11];
  float* out = (float*)d_out;
  char* ws = (char*)d_ws;
  u16*   hb   = (u16*)  (ws + OFF_HB);
  u16*   wct  = (u16*)  (ws + OFF_WCT);
  u16*   wot  = (u16*)  (ws + OFF_WOT);
  u16*   qkv  = (u16*)  (ws + OFF_QKV);
  float* gbuf = (float*)(ws + OFF_G);
  u16*   ebuf = (u16*)  (ws + OFF_EB);
  u16*   kdb  = (u16*)  (ws + OFF_KD);
  u16*   Tb   = (u16*)  (ws + OFF_T);
  u16*   wtilT= (u16*)  (ws + OFF_T);   // overlays T; consumed by gemm MODE0 before phaseA writes T
  float* Dvb  = (float*)(ws + OFF_DV);
  u16*   SPb  = (u16*)  (ws + OFF_SP);
  u16*   onb  = (u16*)  (ws + OFF_ON);

  k_conv_h<<<2048, 256, 0, stream>>>(h, hb);
  k_transpose<<<dim3(32,32), 256, 0, stream>>>(Wq,  wct, 2048, 2048,    0, 2048);
  k_transpose<<<dim3(16,32), 256, 0, stream>>>(Wk,  wct, 2048, 1024, 2048, 2048);
  k_transpose<<<dim3(16,32), 256, 0, stream>>>(Wv,  wct, 2048, 1024, 3072, 2048);
  k_transpose<<<dim3(32,32), 256, 0, stream>>>(Wo,  wot, 2048, 2048,    0, 2048);
  k_wtilde<<<1024, 256, 0, stream>>>(Wg1, Wg2, wtilT);
  gemm8p<256,0><<<320, 512, 0, stream>>>(hb, wct, wtilT, qkv, gbuf, nullptr, bq, bk, bv, bg2);
  k_phaseA<<<dim3(32,8,2), 256, 0, stream>>>(gbuf, qkv, ebuf, kdb, Tb, Dvb);
  k_phaseB<<<dim3(8,8,2), 256, 0, stream>>>(Tb, Dvb, SPb);
  k_phaseC<<<dim3(32,16,2), 256, 0, stream>>>(qkv, ebuf, kdb, SPb, gnw, onb);
  gemm8p<128,1><<<256, 512, 0, stream>>>(onb, wot, nullptr, nullptr, nullptr, out, nullptr, nullptr, nullptr, nullptr);
}

// Round 7
// 640.094 us; speedup vs baseline: 1.0146x; 1.0146x over previous
//
#include <hip/hip_runtime.h>

typedef unsigned short u16;
typedef u16 u16x8 __attribute__((ext_vector_type(8)));
typedef u16 u16x4 __attribute__((ext_vector_type(4)));
typedef __bf16 bf16x8 __attribute__((ext_vector_type(8)));
typedef float f32x4 __attribute__((ext_vector_type(4)));

#define DEVI static __device__ __forceinline__

DEVI float b2f(u16 u){ union { unsigned u; float f; } c; c.u = ((unsigned)u) << 16; return c.f; }
DEVI u16 f2b(float f){ union { float f; unsigned u; } c; c.f = f;
  unsigned r = c.u + 0x7fffu + ((c.u >> 16) & 1u); return (u16)(r >> 16); }
DEVI void gload16(const void* g, void* l){
  __builtin_amdgcn_global_load_lds((const __attribute__((address_space(1))) void*)g,
                                   (__attribute__((address_space(3))) void*)l, 16, 0, 0);
}
DEVI f32x4 MFMA(bf16x8 a, bf16x8 b, f32x4 c){
  return __builtin_amdgcn_mfma_f32_16x16x32_bf16(a, b, c, 0, 0, 0);
}
#define WAITV(n) asm volatile("s_waitcnt vmcnt(" #n ")" ::: "memory")
#define WAITL0() asm volatile("s_waitcnt lgkmcnt(0)" ::: "memory")
#define BAR()    do { __builtin_amdgcn_s_barrier(); asm volatile("" ::: "memory"); } while(0)

// B=2, L=2048, HID=2048, H=16, HKV=8, D=128, CHUNK=64, NC=32, TOK=4096
constexpr size_t OFF_HB  = 0;                                   // h bf16 [4096][2048]
constexpr size_t OFF_WCT = OFF_HB  + (size_t)4096*2048*2;       // WcatT bf16 (Wq|Wk|Wv)^T [4096][2048]
constexpr size_t OFF_WOT = OFF_WCT + (size_t)4224*2048*2;       // WoT bf16 [2048][2048]
constexpr size_t OFF_QKV = OFF_WOT + (size_t)2048*2048*2;       // QKV bf16 [4096][4096]
constexpr size_t OFF_G1  = OFF_QKV + (size_t)4096*4096*2;       // (unused)
constexpr size_t OFF_G   = OFF_G1  + (size_t)4096*16*4;         // g f32 [4096][1024]
constexpr size_t OFF_EB  = OFF_G   + (size_t)4096*1024*4;       // exp(b) bf16 [4096][1024]
constexpr size_t OFF_KD  = OFF_EB  + (size_t)4096*1024*2;       // k*exp(-b) bf16 [4096][1024]
constexpr size_t OFF_T   = OFF_KD  + (size_t)4096*1024*2;       // T bf16 [2][8][32][128][128]; wtilT overlays pre-phaseA
constexpr size_t OFF_DV  = OFF_T   + (size_t)2*8*32*128*128*2;  // Dvec f32 [2][8][32][128]
constexpr size_t OFF_SP  = OFF_DV  + (size_t)2*8*32*128*4;      // S_prefix bf16 [2][8][32][128][128]
constexpr size_t OFF_ON  = OFF_SP  + (size_t)2*8*32*128*128*2;  // o_normed bf16 [4096][2048]

// ---------------- conversion ----------------
__global__ __launch_bounds__(256) void k_conv_h(const float* __restrict__ h, u16* __restrict__ hb){
  int idx = blockIdx.x*256 + threadIdx.x, stride = gridDim.x*256;
  for (int i = idx; i < 4096*2048/4; i += stride){
    float4 v = ((const float4*)h)[i];
    u16x4 o; o[0]=f2b(v.x); o[1]=f2b(v.y); o[2]=f2b(v.z); o[3]=f2b(v.w);
    ((u16x4*)hb)[i] = o;
  }
}

// dst[(rowOff+n)*pitch + k] = bf16(src[k][n])
__global__ __launch_bounds__(256) void k_transpose(const float* __restrict__ src, u16* __restrict__ dst,
                                                   int K, int N, int rowOff, int pitch){
  __shared__ float tile[64][65];
  int kb = blockIdx.y*64, nb = blockIdx.x*64;
  int t = threadIdx.x, x = t & 63, y0 = t >> 6;
#pragma unroll
  for (int i = 0; i < 16; i++){
    int y = y0 + i*4, k = kb + y, n = nb + x;
    tile[y][x] = (n < N) ? src[(size_t)k*N + n] : 0.f;
  }
  __syncthreads();
#pragma unroll
  for (int i = 0; i < 16; i++){
    int y = y0 + i*4, n = nb + y, k = kb + x;
    if (n < N) dst[(size_t)(rowOff + n)*pitch + k] = f2b(tile[x][y]);
  }
}

// ---------------- wtilT[c][r] = bf16( sum_j Wg1[r][j] * Wg2[j][c] ) ----------------
__global__ __launch_bounds__(256) void k_wtilde(const float* __restrict__ Wg1, const float* __restrict__ Wg2,
                                                u16* __restrict__ wt){
  int c = blockIdx.x, t = threadIdx.x;
  float w2[16];
#pragma unroll
  for (int j = 0; j < 16; j++) w2[j] = Wg2[j*1024 + c];
  int r0 = t*8;
  u16x8 o;
#pragma unroll
  for (int u = 0; u < 8; u++){
    const float* row = Wg1 + (size_t)(r0+u)*16;
    float s = 0.f;
#pragma unroll
    for (int j = 0; j < 16; j++) s += row[j]*w2[j];
    o[u] = f2b(s);
  }
  *(u16x8*)&wt[(size_t)c*2048 + r0] = o;
}

// ---------------- pipelined GEMM: 2-buffer, counted vmcnt, conflict-free swizzle ----------------
// C[m][n] = sum_k A[m][k]*Bt[n][k], K=2048, BK=32, BN=256, 8 waves (2x4), wave tile (BM/2)x64.
// LDS layout: [row][4 granules of 16B], stored slot g' = g ^ ((row>>1)&3) -> 2 lanes/bank-quad (free).
// Staging pre-swizzles the GLOBAL source so the linear global_load_lds dest is legal (rule 21).
// MODE 0: QKV+gate epilogue (N=5120, grid 320, 2 blocks/CU). MODE 1: fp32 store (N=2048, grid 256, 3 blocks/CU).
template<int BM, int MODE>
__global__ __launch_bounds__(512, 2) void gemmP(const u16* __restrict__ A,
                                                const u16* __restrict__ BtLo,
                                                const u16* __restrict__ BtHi,
                                                u16* __restrict__ Cq, float* __restrict__ Cg,
                                                float* __restrict__ Cf,
                                                const float* __restrict__ bq,
                                                const float* __restrict__ bk,
                                                const float* __restrict__ bv,
                                                const float* __restrict__ bg2){
  constexpr int NT = 64;             // K/32
  constexpr int MI = BM/32;          // A fragments per wave per K-tile
  constexpr int ALOADS = BM/128;     // per-thread A gloads per K-tile
  constexpr int NTN = (MODE==0) ? 20 : 8;
  constexpr int CPX = (MODE==0) ? 40 : 32;
  __shared__ u16 sA[2*BM*32];
  __shared__ u16 sB[2*256*32];
  int id = blockIdx.x;
  int swz = (id & 7)*CPX + (id >> 3);          // bijective: grid = 8*CPX
  int mt = swz / NTN, nt = swz % NTN;
  int t = threadIdx.x, w = t >> 6, l = t & 63;
  int wr = w >> 2, wc = w & 3;
  int mRow0 = mt*BM, nCol0 = nt*256;
  const u16* Bbase = (MODE==0 && nCol0 >= 4096) ? (BtHi + (size_t)(nCol0-4096)*2048)
                                                : (BtLo + (size_t)nCol0*2048);
  // staging sources: pre-swizzled granule within each row
  const u16* srcA[ALOADS]; const u16* srcB[2];
#pragma unroll
  for (int i = 0; i < ALOADS; i++){
    int S = t + i*512, r = S>>2, g = (S&3) ^ ((r>>1)&3);
    srcA[i] = A + (size_t)(mRow0 + r)*2048 + g*8;
  }
#pragma unroll
  for (int i = 0; i < 2; i++){
    int S = t + i*512, r = S>>2, g = (S&3) ^ ((r>>1)&3);
    srcB[i] = Bbase + (size_t)r*2048 + g*8;
  }
  auto ISSUE = [&](int T){
    int buf = T & 1;
    u16* dA = sA + buf*(BM*32);
    u16* dB = sB + buf*(256*32);
#pragma unroll
    for (int i = 0; i < ALOADS; i++) gload16(srcA[i] + T*32, dA + (i*512 + w*64)*8);
#pragma unroll
    for (int i = 0; i < 2; i++)      gload16(srcB[i] + T*32, dB + (i*512 + w*64)*8);
  };
  f32x4 acc[MI][4] = {};
  ISSUE(0); ISSUE(1);
  for (int T = 0; T < NT; ++T){
    if (T == NT-1) WAITV(0);
    else { if constexpr (BM==256) WAITV(4); else WAITV(3); }
    BAR();
    const u16* bufA = sA + (T&1)*(BM*32);
    const u16* bufB = sB + (T&1)*(256*32);
    bf16x8 bfr[4], afr[MI];
#pragma unroll
    for (int ni = 0; ni < 4; ni++){
      int r = wc*64 + ni*16 + (l&15);
      int p = (l>>4) ^ ((r>>1)&3);
      bfr[ni] = *(const bf16x8*)&bufB[(r*4 + p)*8];
    }
#pragma unroll
    for (int mi = 0; mi < MI; mi++){
      int r = wr*(BM/2) + mi*16 + (l&15);
      int p = (l>>4) ^ ((r>>1)&3);
      afr[mi] = *(const bf16x8*)&bufA[(r*4 + p)*8];
    }
    __builtin_amdgcn_s_setprio(1);
#pragma unroll
    for (int mi = 0; mi < MI; mi++)
#pragma unroll
      for (int ni = 0; ni < 4; ni++)
        acc[mi][ni] = MFMA(afr[mi], bfr[ni], acc[mi][ni]);
    __builtin_amdgcn_s_setprio(0);
    WAITL0();
    BAR();
    if (T + 2 < NT) ISSUE(T + 2);
  }
  // epilogue
  int iLoc = (l>>4)*4, jc = l & 15;
  if (MODE == 0){
#pragma unroll
    for (int ni = 0; ni < 4; ni++){
      int n0 = nCol0 + wc*64 + ni*16;
      int n = n0 + jc;
      int kind; float bias;
      if (n0 < 2048){ kind = 0; bias = bq[n]; }
      else if (n0 < 3072){ kind = 1; bias = bk[n - 2048]; }
      else if (n0 < 4096){ kind = 2; bias = bv[n - 3072]; }
      else { kind = 3; bias = bg2[n - 4096]; }
#pragma unroll
      for (int mi = 0; mi < MI; mi++){
        int m = mRow0 + wr*(BM/2) + mi*16 + iLoc;
#pragma unroll
        for (int rr = 0; rr < 4; rr++){
          float x = acc[mi][ni][rr] + bias;
          int row = m + rr;
          if (kind == 0)      Cq[(size_t)row*4096 + n] = f2b(fmaxf(x, 0.f) * 0.08838834764831845f);
          else if (kind == 1) Cq[(size_t)row*4096 + n] = f2b(fmaxf(x, 0.f));
          else if (kind == 2) Cq[(size_t)row*4096 + n] = f2b(x);
          else Cg[(size_t)row*1024 + (n - 4096)] = (fminf(x,0.f) - log1pf(expf(-fabsf(x)))) * 0.0625f;
        }
      }
    }
  } else {
#pragma unroll
    for (int ni = 0; ni < 4; ni++){
      int n = nCol0 + wc*64 + ni*16 + jc;
#pragma unroll
      for (int mi = 0; mi < MI; mi++){
        int m = mRow0 + wr*(BM/2) + mi*16 + iLoc;
#pragma unroll
        for (int rr = 0; rr < 4; rr++) Cf[(size_t)(m+rr)*2048 + n] = acc[mi][ni][rr];
      }
    }
  }
}

// ---------------- phase A ----------------
__global__ __launch_bounds__(256) void k_phaseA(const float* __restrict__ g, const u16* __restrict__ QKV,
                                                u16* __restrict__ eb, u16* __restrict__ kd,
                                                u16* __restrict__ T, float* __restrict__ Dv){
  __shared__ float gb[64*128];
  __shared__ u16 keT[128*72];
  __shared__ u16 vT [128*72];
  int c = blockIdx.x, kvh = blockIdx.y, b = blockIdx.z;
  int t = threadIdx.x;
  int tok0 = b*2048 + c*64;
#pragma unroll
  for (int r = 0; r < 8; r++){
    int idx4 = r*256 + t;
    int i = idx4 >> 5, c4 = idx4 & 31;
    ((float4*)gb)[i*32 + c4] = *(const float4*)&g[(size_t)(tok0+i)*1024 + kvh*128 + c4*4];
  }
  __syncthreads();
  if (t < 128){
    float run = 0.f;
    for (int i = 0; i < 64; i++){ run += gb[i*128 + t]; gb[i*128 + t] = run; }
    Dv[((size_t)(b*8+kvh)*32 + c)*128 + t] = expf(run);
  }
  __syncthreads();
  int d0 = (t&15)*8;
  float blast[8];
#pragma unroll
  for (int j = 0; j < 8; j++) blast[j] = gb[63*128 + d0 + j];
#pragma unroll
  for (int r = 0; r < 4; r++){
    int i = (t>>4) + r*16;
    u16x8 kv_ = *(const u16x8*)&QKV[(size_t)(tok0+i)*4096 + 2048 + kvh*128 + d0];
    u16x8 vv  = *(const u16x8*)&QKV[(size_t)(tok0+i)*4096 + 3072 + kvh*128 + d0];
    u16x8 ebv, kdv;
#pragma unroll
    for (int j = 0; j < 8; j++){
      float bcur = gb[i*128 + d0 + j];
      float kf = b2f(kv_[j]);
      ebv[j] = f2b(expf(bcur));
      kdv[j] = f2b(kf * expf(-bcur));
      keT[(d0+j)*72 + i] = f2b(kf * expf(blast[j] - bcur));
      vT [(d0+j)*72 + i] = vv[j];
    }
    *(u16x8*)&eb[(size_t)(tok0+i)*1024 + kvh*128 + d0] = ebv;
    *(u16x8*)&kd[(size_t)(tok0+i)*1024 + kvh*128 + d0] = kdv;
  }
  __syncthreads();
  int w = t>>6, l = t&63;
  f32x4 acc[2][8] = {};
#pragma unroll
  for (int ks = 0; ks < 2; ks++){
    bf16x8 af[2];
#pragma unroll
    for (int ti = 0; ti < 2; ti++)
      af[ti] = *(const bf16x8*)&keT[(w*32 + ti*16 + (l&15))*72 + ks*32 + (l>>4)*8];
#pragma unroll
    for (int tj = 0; tj < 8; tj++){
      bf16x8 bf_ = *(const bf16x8*)&vT[(tj*16 + (l&15))*72 + ks*32 + (l>>4)*8];
#pragma unroll
      for (int ti = 0; ti < 2; ti++) acc[ti][tj] = MFMA(af[ti], bf_, acc[ti][tj]);
    }
  }
  size_t tbase = ((size_t)(b*8+kvh)*32 + c)*16384;
#pragma unroll
  for (int ti = 0; ti < 2; ti++)
#pragma unroll
    for (int tj = 0; tj < 8; tj++)
#pragma unroll
      for (int rr = 0; rr < 4; rr++){
        int d = w*32 + ti*16 + (l>>4)*4 + rr, e = tj*16 + (l&15);
        T[tbase + d*128 + e] = f2b(acc[ti][tj][rr]);
      }
}

// ---------------- phase B ----------------
__global__ __launch_bounds__(256) void k_phaseB(const u16* __restrict__ T, const float* __restrict__ Dv,
                                                u16* __restrict__ SP){
  __shared__ u16 sl[16*128];
  int es = blockIdx.x, kvh = blockIdx.y, b = blockIdx.z;
  int t = threadIdx.x;
  size_t bh = (size_t)(b*8 + kvh);
  float S[8] = {0,0,0,0,0,0,0,0};
  for (int c = 0; c < 32; c++){
#pragma unroll
    for (int r = 0; r < 8; r++){
      int idx = r*256 + t, d = idx>>4, el = idx&15;
      sl[el*128 + d] = f2b(S[r]);
    }
    __syncthreads();
    size_t spb = (bh*32 + c)*16384 + (size_t)es*2048;
    *(u16x8*)&SP[spb + t*8] = *(const u16x8*)&sl[t*8];
    size_t tb  = (bh*32 + c)*16384;
    size_t dvb = (bh*32 + c)*128;
#pragma unroll
    for (int r = 0; r < 8; r++){
      int idx = r*256 + t, d = idx>>4, el = idx&15;
      float tv = b2f(T[tb + d*128 + es*16 + el]);
      S[r] = S[r]*Dv[dvb + d] + tv;
    }
    __syncthreads();
  }
}

// ---------------- phase C ----------------
__global__ __launch_bounds__(256) void k_phaseC(const u16* __restrict__ QKV, const u16* __restrict__ eb,
                                                const u16* __restrict__ kd, const u16* __restrict__ SP,
                                                const float* __restrict__ gnw, u16* __restrict__ onrm){
  __shared__ u16 kl[64*128];
  __shared__ u16 sl[64*72];
  __shared__ u16 vT[128*72];
  int c = blockIdx.x, h = blockIdx.y, b = blockIdx.z;
  int kvh = h >> 1;
  int t = threadIdx.x, w = t>>6, l = t&63;
  int tok0 = b*2048 + c*64;
#pragma unroll
  for (int is = 0; is < 4; is++){
    int row = (t>>4) + is*16;
    int d0s = 8*((t&15) ^ (row&7));
    gload16(&kd[(size_t)(tok0+row)*1024 + kvh*128 + d0s], &kl[is*2048 + w*512]);
  }
  int d0v = (t&15)*8;
#pragma unroll
  for (int r = 0; r < 4; r++){
    int i = (t>>4) + r*16;
    u16x8 vv = *(const u16x8*)&QKV[(size_t)(tok0+i)*4096 + 3072 + kvh*128 + d0v];
#pragma unroll
    for (int jj = 0; jj < 8; jj++) vT[(d0v+jj)*72 + i] = vv[jj];
  }
  bf16x8 aq[4];
  {
    int i = w*16 + (l&15);
#pragma unroll
    for (int kt = 0; kt < 4; kt++){
      int dq = kt*32 + (l>>4)*8;
      u16x8 qv = *(const u16x8*)&QKV[(size_t)(tok0+i)*4096 + h*128 + dq];
      u16x8 ev = *(const u16x8*)&eb[(size_t)(tok0+i)*1024 + kvh*128 + dq];
      u16x8 o;
#pragma unroll
      for (int jj = 0; jj < 8; jj++) o[jj] = f2b(b2f(qv[jj]) * b2f(ev[jj]));
      aq[kt] = __builtin_bit_cast(bf16x8, o);
    }
  }
  __syncthreads();
  f32x4 accs[4] = {};
#pragma unroll
  for (int kt = 0; kt < 4; kt++){
#pragma unroll
    for (int jt = 0; jt < 4; jt++){
      int j = jt*16 + (l&15);
      int byte_ = j*256 + ((2*(kt*32 + (l>>4)*8)) ^ ((j&7)<<4));
      bf16x8 bk_ = *(const bf16x8*)((const char*)kl + byte_);
      accs[jt] = MFMA(aq[kt], bk_, accs[jt]);
    }
  }
#pragma unroll
  for (int jt = 0; jt < 4; jt++)
#pragma unroll
    for (int rr = 0; rr < 4; rr++){
      int i = w*16 + (l>>4)*4 + rr;
      int j = jt*16 + (l&15);
      sl[i*72 + j] = f2b((i >= j) ? accs[jt][rr] : 0.f);
    }
  f32x4 acco[8] = {};
  size_t spb = ((size_t)(b*8+kvh)*32 + c)*16384;
#pragma unroll
  for (int kt = 0; kt < 4; kt++){
#pragma unroll
    for (int et = 0; et < 8; et++){
      int e = et*16 + (l&15);
      int dd = kt*32 + (l>>4)*8;
      bf16x8 bs = *(const bf16x8*)&SP[spb + (size_t)e*128 + dd];
      acco[et] = MFMA(aq[kt], bs, acco[et]);
    }
  }
#pragma unroll
  for (int kt2 = 0; kt2 < 2; kt2++){
    int i = w*16 + (l&15);
    bf16x8 as = *(const bf16x8*)&sl[i*72 + kt2*32 + (l>>4)*8];
#pragma unroll
    for (int et = 0; et < 8; et++){
      bf16x8 bv_ = *(const bf16x8*)&vT[(et*16 + (l&15))*72 + kt2*32 + (l>>4)*8];
      acco[et] = MFMA(as, bv_, acco[et]);
    }
  }
  float gw[8];
#pragma unroll
  for (int et = 0; et < 8; et++) gw[et] = gnw[et*16 + (l&15)];
#pragma unroll
  for (int rr = 0; rr < 4; rr++){
    int i = w*16 + (l>>4)*4 + rr;
    float ss = 0.f;
#pragma unroll
    for (int et = 0; et < 8; et++){ float x = acco[et][rr]; ss += x*x; }
    ss += __shfl_xor(ss, 1); ss += __shfl_xor(ss, 2);
    ss += __shfl_xor(ss, 4); ss += __shfl_xor(ss, 8);
    float sc = rsqrtf(ss*(1.f/128.f) + 1e-5f);
#pragma unroll
    for (int et = 0; et < 8; et++){
      int e = et*16 + (l&15);
      onrm[(size_t)(tok0+i)*2048 + h*128 + e] = f2b(acco[et][rr]*sc*gw[et]);
    }
  }
}

extern "C" void kernel_launch(void* const* d_in, const int* in_sizes, int n_in,
                              void* d_out, int out_size, void* d_ws, size_t ws_size,
                              hipStream_t stream){
  (void)in_sizes; (void)n_in; (void)out_size; (void)ws_size;
  const float* h   = (const float*)d_in[0];
  const float* Wq  = (const float*)d_in[1];
  const float* bq  = (const float*)d_in[2];
  const float* Wk  = (const float*)d_in[3];
  const float* bk  = (const float*)d_in[4];
  const float* Wv  = (const float*)d_in[5];
  const float* bv  = (const float*)d_in[6];
  const float* Wg1 = (const float*)d_in[7];
  const float* Wg2 = (const float*)d_in[8];
  const float* bg2 = (const float*)d_in[9];
  const float* gnw = (const float*)d_in[10];
  const float* Wo  = (const float*)d_in[11];
  float* out = (float*)d_out;
  char* ws = (char*)d_ws;
  u16*   hb   = (u16*)  (ws + OFF_HB);
  u16*   wct  = (u16*)  (ws + OFF_WCT);
  u16*   wot  = (u16*)  (ws + OFF_WOT);
  u16*   qkv  = (u16*)  (ws + OFF_QKV);
  float* gbuf = (float*)(ws + OFF_G);
  u16*   ebuf = (u16*)  (ws + OFF_EB);
  u16*   kdb  = (u16*)  (ws + OFF_KD);
  u16*   Tb   = (u16*)  (ws + OFF_T);
  u16*   wtilT= (u16*)  (ws + OFF_T);   // overlays T; consumed by gemm MODE0 before phaseA writes T
  float* Dvb  = (float*)(ws + OFF_DV);
  u16*   SPb  = (u16*)  (ws + OFF_SP);
  u16*   onb  = (u16*)  (ws + OFF_ON);

  k_conv_h<<<2048, 256, 0, stream>>>(h, hb);
  k_transpose<<<dim3(32,32), 256, 0, stream>>>(Wq,  wct, 2048, 2048,    0, 2048);
  k_transpose<<<dim3(16,32), 256, 0, stream>>>(Wk,  wct, 2048, 1024, 2048, 2048);
  k_transpose<<<dim3(16,32), 256, 0, stream>>>(Wv,  wct, 2048, 1024, 3072, 2048);
  k_transpose<<<dim3(32,32), 256, 0, stream>>>(Wo,  wot, 2048, 2048,    0, 2048);
  k_wtilde<<<1024, 256, 0, stream>>>(Wg1, Wg2, wtilT);
  gemmP<256,0><<<320, 512, 0, stream>>>(hb, wct, wtilT, qkv, gbuf, nullptr, bq, bk, bv, bg2);
  k_phaseA<<<dim3(32,8,2), 256, 0, stream>>>(gbuf, qkv, ebuf, kdb, Tb, Dvb);
  k_phaseB<<<dim3(8,8,2), 256, 0, stream>>>(Tb, Dvb, SPb);
  k_phaseC<<<dim3(32,16,2), 256, 0, stream>>>(qkv, ebuf, kdb, SPb, gnw, onb);
  gemmP<128,1><<<256, 512, 0, stream>>>(onb, wot, nullptr, nullptr, nullptr, out, nullptr, nullptr, nullptr, nullptr);
}

// Round 8
// 475.789 us; speedup vs baseline: 1.3650x; 1.3453x over previous
//
#include <hip/hip_runtime.h>

typedef unsigned short u16;
typedef u16 u16x8 __attribute__((ext_vector_type(8)));
typedef u16 u16x4 __attribute__((ext_vector_type(4)));
typedef __bf16 bf16x8 __attribute__((ext_vector_type(8)));
typedef float f32x4 __attribute__((ext_vector_type(4)));

#define DEVI static __device__ __forceinline__

DEVI float b2f(u16 u){ union { unsigned u; float f; } c; c.u = ((unsigned)u) << 16; return c.f; }
DEVI u16 f2b(float f){ union { float f; unsigned u; } c; c.f = f;
  unsigned r = c.u + 0x7fffu + ((c.u >> 16) & 1u); return (u16)(r >> 16); }
DEVI void gload16(const void* g, void* l){
  __builtin_amdgcn_global_load_lds((const __attribute__((address_space(1))) void*)g,
                                   (__attribute__((address_space(3))) void*)l, 16, 0, 0);
}
DEVI f32x4 MFMA(bf16x8 a, bf16x8 b, f32x4 c){
  return __builtin_amdgcn_mfma_f32_16x16x32_bf16(a, b, c, 0, 0, 0);
}
#define WAITV(n) asm volatile("s_waitcnt vmcnt(" #n ")" ::: "memory")
#define WAITL0() asm volatile("s_waitcnt lgkmcnt(0)" ::: "memory")

// B=2, L=2048, HID=2048, H=16, HKV=8, D=128, CHUNK=64, NC=32, TOK=4096
constexpr size_t OFF_HB  = 0;                                   // h bf16 [4096][2048]
constexpr size_t OFF_WCT = OFF_HB  + (size_t)4096*2048*2;       // WcatT bf16 (Wq|Wk|Wv)^T [4096][2048]
constexpr size_t OFF_WOT = OFF_WCT + (size_t)4224*2048*2;       // WoT bf16 [2048][2048]
constexpr size_t OFF_QKV = OFF_WOT + (size_t)2048*2048*2;       // QKV bf16 [4096][4096]
constexpr size_t OFF_G1  = OFF_QKV + (size_t)4096*4096*2;       // (unused)
constexpr size_t OFF_G   = OFF_G1  + (size_t)4096*16*4;         // g f32 [4096][1024] raw logits; phaseA applies logsigmoid
constexpr size_t OFF_EB  = OFF_G   + (size_t)4096*1024*4;       // exp(b) bf16 [4096][1024]
constexpr size_t OFF_KD  = OFF_EB  + (size_t)4096*1024*2;       // k*exp(-b) bf16 [4096][1024]
constexpr size_t OFF_T   = OFF_KD  + (size_t)4096*1024*2;       // T bf16 [2][8][32][128][128]; wtilT overlays pre-phaseA
constexpr size_t OFF_DV  = OFF_T   + (size_t)2*8*32*128*128*2;  // Dvec f32 [2][8][32][128]
constexpr size_t OFF_SP  = OFF_DV  + (size_t)2*8*32*128*4;      // S_prefix bf16 [2][8][32][128][128]
constexpr size_t OFF_ON  = OFF_SP  + (size_t)2*8*32*128*128*2;  // o_normed bf16 [4096][2048]

// ---------------- conversion ----------------
__global__ __launch_bounds__(256) void k_conv_h(const float* __restrict__ h, u16* __restrict__ hb){
  int idx = blockIdx.x*256 + threadIdx.x, stride = gridDim.x*256;
  for (int i = idx; i < 4096*2048/4; i += stride){
    float4 v = ((const float4*)h)[i];
    u16x4 o; o[0]=f2b(v.x); o[1]=f2b(v.y); o[2]=f2b(v.z); o[3]=f2b(v.w);
    ((u16x4*)hb)[i] = o;
  }
}

// dst[(rowOff+n)*pitch + k] = bf16(src[k][n])
__global__ __launch_bounds__(256) void k_transpose(const float* __restrict__ src, u16* __restrict__ dst,
                                                   int K, int N, int rowOff, int pitch){
  __shared__ float tile[64][65];
  int kb = blockIdx.y*64, nb = blockIdx.x*64;
  int t = threadIdx.x, x = t & 63, y0 = t >> 6;
#pragma unroll
  for (int i = 0; i < 16; i++){
    int y = y0 + i*4, k = kb + y, n = nb + x;
    tile[y][x] = (n < N) ? src[(size_t)k*N + n] : 0.f;
  }
  __syncthreads();
#pragma unroll
  for (int i = 0; i < 16; i++){
    int y = y0 + i*4, n = nb + y, k = kb + x;
    if (n < N) dst[(size_t)(rowOff + n)*pitch + k] = f2b(tile[x][y]);
  }
}

// ---------------- wtilT[c][r] = bf16( sum_j Wg1[r][j] * Wg2[j][c] ) ; grid 128 x 8 cols ----------------
__global__ __launch_bounds__(256) void k_wtilde(const float* __restrict__ Wg1, const float* __restrict__ Wg2,
                                                u16* __restrict__ wt){
  __shared__ float w2s[16*8];
  int c0 = blockIdx.x*8, t = threadIdx.x;
  if (t < 128){ int j = t>>3, cc = t&7; w2s[j*8+cc] = Wg2[j*1024 + c0 + cc]; }
  __syncthreads();
  int r0 = t*8;
#pragma unroll
  for (int half = 0; half < 2; half++){
    float rowv[4][16];
#pragma unroll
    for (int u = 0; u < 4; u++)
#pragma unroll
      for (int j4 = 0; j4 < 4; j4++)
        *(float4*)&rowv[u][j4*4] = *(const float4*)&Wg1[(size_t)(r0 + half*4 + u)*16 + j4*4];
#pragma unroll
    for (int cc = 0; cc < 8; cc++){
      u16x4 o;
#pragma unroll
      for (int u = 0; u < 4; u++){
        float s = 0.f;
#pragma unroll
        for (int j = 0; j < 16; j++) s += rowv[u][j]*w2s[j*8+cc];
        o[u] = f2b(s);
      }
      *(u16x4*)&wt[(size_t)(c0+cc)*2048 + r0 + half*4] = o;
    }
  }
}

// ---------------- pipelined 256-col GEMM (round-3 proven structure, fixed swizzle) ----------------
// C[m][n] = sum_k A[m][k]*Bt[n][k], K=2048. BM x 256 tile, 8 waves (2x4), 4 LDS buffers BK=32, depth-3 prefetch.
// LDS: [row][4 granules 16B], slot g' = g ^ ((r>>1)&3) -> 0 bank conflicts (verified r6/r7).
// MODE 0: QKV epilogue (bias+relu+scale, bf16, N=4096). MODE 1: fp32 store (N=2048).
template<int BM, int MODE>
__global__ __launch_bounds__(512, 2) void gemm256(const u16* __restrict__ A, const u16* __restrict__ Bt,
                                                  u16* __restrict__ Cq, float* __restrict__ Cf,
                                                  const float* __restrict__ bq, const float* __restrict__ bk,
                                                  const float* __restrict__ bv){
  constexpr int NT = 64;             // K/32
  constexpr int MI = BM/32;          // A fragments per wave per K-tile
  constexpr int ALOADS = BM/128;     // per-thread A gloads per K-tile
  constexpr int NTN = (MODE==0) ? 16 : 8;
  __shared__ u16 sA[4*BM*32];
  __shared__ u16 sB[4*256*32];
  int id = blockIdx.x;
  int swz = (id & 7)*32 + (id >> 3);           // grid 256, bijective
  int mt = swz / NTN, nt = swz % NTN;
  int t = threadIdx.x, w = t >> 6, l = t & 63;
  int wr = w >> 2, wc = w & 3;                 // wave grid 2x4, wave tile (BM/2)x64
  int mRow0 = mt*BM, nCol0 = nt*256;
  const u16* srcA[ALOADS]; const u16* srcB[2];
#pragma unroll
  for (int i = 0; i < ALOADS; i++){
    int S = t + i*512, r = S>>2, g = (S&3) ^ ((r>>1)&3);
    srcA[i] = A + (size_t)(mRow0 + r)*2048 + g*8;
  }
#pragma unroll
  for (int i = 0; i < 2; i++){
    int S = t + i*512, r = S>>2, g = (S&3) ^ ((r>>1)&3);
    srcB[i] = Bt + (size_t)(nCol0 + r)*2048 + g*8;
  }
  auto ISSUE = [&](int T){
    int buf = T & 3;
    u16* dA = sA + buf*(BM*32);
    u16* dB = sB + buf*(256*32);
#pragma unroll
    for (int i = 0; i < ALOADS; i++) gload16(srcA[i] + T*32, dA + (i*512 + w*64)*8);
#pragma unroll
    for (int i = 0; i < 2; i++)      gload16(srcB[i] + T*32, dB + (i*512 + w*64)*8);
  };
  f32x4 acc[MI][4] = {};
  ISSUE(0); ISSUE(1); ISSUE(2);
  for (int T = 0; T < NT; ++T){
    if (T + 3 < NT) ISSUE(T + 3);
    if constexpr (BM == 256){        // 4 loads/tile
      if (T < NT-3)       WAITV(12);
      else if (T == NT-3) WAITV(8);
      else if (T == NT-2) WAITV(4);
      else                WAITV(0);
    } else {                         // 3 loads/tile
      if (T < NT-3)       WAITV(9);
      else if (T == NT-3) WAITV(6);
      else if (T == NT-2) WAITV(3);
      else                WAITV(0);
    }
    __builtin_amdgcn_s_barrier();
    const u16* bufA = sA + (T&3)*(BM*32);
    const u16* bufB = sB + (T&3)*(256*32);
    bf16x8 bfr[4], afr[MI];
#pragma unroll
    for (int ni = 0; ni < 4; ni++){
      int r = wc*64 + ni*16 + (l&15);
      int p = (l>>4) ^ ((r>>1)&3);
      bfr[ni] = *(const bf16x8*)&bufB[(r*4 + p)*8];
    }
#pragma unroll
    for (int mi = 0; mi < MI; mi++){
      int r = wr*(BM/2) + mi*16 + (l&15);
      int p = (l>>4) ^ ((r>>1)&3);
      afr[mi] = *(const bf16x8*)&bufA[(r*4 + p)*8];
    }
    __builtin_amdgcn_s_setprio(1);
#pragma unroll
    for (int mi = 0; mi < MI; mi++)
#pragma unroll
      for (int ni = 0; ni < 4; ni++)
        acc[mi][ni] = MFMA(afr[mi], bfr[ni], acc[mi][ni]);
    __builtin_amdgcn_s_setprio(0);
    WAITL0();
    __builtin_amdgcn_s_barrier();
  }
  // epilogue
  int iLoc = (l>>4)*4, jc = l & 15;
  if (MODE == 0){
#pragma unroll
    for (int ni = 0; ni < 4; ni++){
      int n0 = nCol0 + wc*64 + ni*16;
      int n = n0 + jc;
      int kind; float bias;
      if (n0 < 2048){ kind = 0; bias = bq[n]; }
      else if (n0 < 3072){ kind = 1; bias = bk[n - 2048]; }
      else { kind = 2; bias = bv[n - 3072]; }
#pragma unroll
      for (int mi = 0; mi < MI; mi++){
        int m = mRow0 + wr*(BM/2) + mi*16 + iLoc;
#pragma unroll
        for (int rr = 0; rr < 4; rr++){
          float x = acc[mi][ni][rr] + bias;
          int row = m + rr;
          if (kind == 0)      Cq[(size_t)row*4096 + n] = f2b(fmaxf(x, 0.f) * 0.08838834764831845f);
          else if (kind == 1) Cq[(size_t)row*4096 + n] = f2b(fmaxf(x, 0.f));
          else                Cq[(size_t)row*4096 + n] = f2b(x);
        }
      }
    }
  } else {
#pragma unroll
    for (int ni = 0; ni < 4; ni++){
      int n = nCol0 + wc*64 + ni*16 + jc;
#pragma unroll
      for (int mi = 0; mi < MI; mi++){
        int m = mRow0 + wr*(BM/2) + mi*16 + iLoc;
#pragma unroll
        for (int rr = 0; rr < 4; rr++) Cf[(size_t)(m+rr)*2048 + n] = acc[mi][ni][rr];
      }
    }
  }
}

// ---------------- gate GEMM: logits = hb @ wtil + bg2 (raw f32) ----------------
// M=4096, N=1024, K=2048; BM=BN=128, BK=32, 4 waves (2x2), 4 LDS buffers, depth-3. 2 blocks/CU.
__global__ __launch_bounds__(256, 2) void gemmG(const u16* __restrict__ A, const u16* __restrict__ Bt,
                                                float* __restrict__ Cg, const float* __restrict__ bg2){
  constexpr int NT = 64;
  __shared__ u16 sA[4*128*32];
  __shared__ u16 sB[4*128*32];
  int id = blockIdx.x;
  int swz = (id & 7)*32 + (id >> 3);           // grid 256, bijective
  int mt = swz >> 3, nt = swz & 7;             // 32 x 8
  int t = threadIdx.x, w = t >> 6, l = t & 63;
  int wr = w >> 1, wc = w & 1;                 // wave grid 2x2, wave tile 64x64
  int mRow0 = mt*128, nCol0 = nt*128;
  const u16* srcA[2]; const u16* srcB[2];
#pragma unroll
  for (int i = 0; i < 2; i++){
    int S = t + i*256, r = S>>2, g = (S&3) ^ ((r>>1)&3);
    srcA[i] = A + (size_t)(mRow0 + r)*2048 + g*8;
    srcB[i] = Bt + (size_t)(nCol0 + r)*2048 + g*8;
  }
  auto ISSUE = [&](int T){
    int buf = T & 3;
    u16* dA = sA + buf*4096;
    u16* dB = sB + buf*4096;
#pragma unroll
    for (int i = 0; i < 2; i++) gload16(srcA[i] + T*32, dA + (i*256 + w*64)*8);
#pragma unroll
    for (int i = 0; i < 2; i++) gload16(srcB[i] + T*32, dB + (i*256 + w*64)*8);
  };
  f32x4 acc[4][4] = {};
  ISSUE(0); ISSUE(1); ISSUE(2);
  for (int T = 0; T < NT; ++T){
    if (T + 3 < NT) ISSUE(T + 3);
    if (T < NT-3)       WAITV(12);
    else if (T == NT-3) WAITV(8);
    else if (T == NT-2) WAITV(4);
    else                WAITV(0);
    __builtin_amdgcn_s_barrier();
    const u16* bufA = sA + (T&3)*4096;
    const u16* bufB = sB + (T&3)*4096;
    bf16x8 bfr[4], afr[4];
#pragma unroll
    for (int ni = 0; ni < 4; ni++){
      int r = wc*64 + ni*16 + (l&15);
      int p = (l>>4) ^ ((r>>1)&3);
      bfr[ni] = *(const bf16x8*)&bufB[(r*4 + p)*8];
    }
#pragma unroll
    for (int mi = 0; mi < 4; mi++){
      int r = wr*64 + mi*16 + (l&15);
      int p = (l>>4) ^ ((r>>1)&3);
      afr[mi] = *(const bf16x8*)&bufA[(r*4 + p)*8];
    }
    __builtin_amdgcn_s_setprio(1);
#pragma unroll
    for (int mi = 0; mi < 4; mi++)
#pragma unroll
      for (int ni = 0; ni < 4; ni++)
        acc[mi][ni] = MFMA(afr[mi], bfr[ni], acc[mi][ni]);
    __builtin_amdgcn_s_setprio(0);
    WAITL0();
    __builtin_amdgcn_s_barrier();
  }
  int iLoc = (l>>4)*4, jc = l & 15;
#pragma unroll
  for (int ni = 0; ni < 4; ni++){
    int n = nCol0 + wc*64 + ni*16 + jc;
    float bias = bg2[n];
#pragma unroll
    for (int mi = 0; mi < 4; mi++){
      int m = mRow0 + wr*64 + mi*16 + iLoc;
#pragma unroll
      for (int rr = 0; rr < 4; rr++) Cg[(size_t)(m+rr)*1024 + n] = acc[mi][ni][rr] + bias;
    }
  }
}

// ---------------- phase A (applies logsigmoid/16 to raw logits while staging) ----------------
__global__ __launch_bounds__(256) void k_phaseA(const float* __restrict__ g, const u16* __restrict__ QKV,
                                                u16* __restrict__ eb, u16* __restrict__ kd,
                                                u16* __restrict__ T, float* __restrict__ Dv){
  __shared__ float gb[64*128];
  __shared__ u16 keT[128*72];
  __shared__ u16 vT [128*72];
  int c = blockIdx.x, kvh = blockIdx.y, b = blockIdx.z;
  int t = threadIdx.x;
  int tok0 = b*2048 + c*64;
#pragma unroll
  for (int r = 0; r < 8; r++){
    int idx4 = r*256 + t;
    int i = idx4 >> 5, c4 = idx4 & 31;
    float4 v = *(const float4*)&g[(size_t)(tok0+i)*1024 + kvh*128 + c4*4];
    float4 o;
    o.x = (fminf(v.x,0.f) - log1pf(expf(-fabsf(v.x)))) * 0.0625f;
    o.y = (fminf(v.y,0.f) - log1pf(expf(-fabsf(v.y)))) * 0.0625f;
    o.z = (fminf(v.z,0.f) - log1pf(expf(-fabsf(v.z)))) * 0.0625f;
    o.w = (fminf(v.w,0.f) - log1pf(expf(-fabsf(v.w)))) * 0.0625f;
    ((float4*)gb)[i*32 + c4] = o;
  }
  __syncthreads();
  if (t < 128){
    float run = 0.f;
    for (int i = 0; i < 64; i++){ run += gb[i*128 + t]; gb[i*128 + t] = run; }
    Dv[((size_t)(b*8+kvh)*32 + c)*128 + t] = expf(run);
  }
  __syncthreads();
  int d0 = (t&15)*8;
  float blast[8];
#pragma unroll
  for (int j = 0; j < 8; j++) blast[j] = gb[63*128 + d0 + j];
#pragma unroll
  for (int r = 0; r < 4; r++){
    int i = (t>>4) + r*16;
    u16x8 kv_ = *(const u16x8*)&QKV[(size_t)(tok0+i)*4096 + 2048 + kvh*128 + d0];
    u16x8 vv  = *(const u16x8*)&QKV[(size_t)(tok0+i)*4096 + 3072 + kvh*128 + d0];
    u16x8 ebv, kdv;
#pragma unroll
    for (int j = 0; j < 8; j++){
      float bcur = gb[i*128 + d0 + j];
      float kf = b2f(kv_[j]);
      ebv[j] = f2b(expf(bcur));
      kdv[j] = f2b(kf * expf(-bcur));
      keT[(d0+j)*72 + i] = f2b(kf * expf(blast[j] - bcur));
      vT [(d0+j)*72 + i] = vv[j];
    }
    *(u16x8*)&eb[(size_t)(tok0+i)*1024 + kvh*128 + d0] = ebv;
    *(u16x8*)&kd[(size_t)(tok0+i)*1024 + kvh*128 + d0] = kdv;
  }
  __syncthreads();
  int w = t>>6, l = t&63;
  f32x4 acc[2][8] = {};
#pragma unroll
  for (int ks = 0; ks < 2; ks++){
    bf16x8 af[2];
#pragma unroll
    for (int ti = 0; ti < 2; ti++)
      af[ti] = *(const bf16x8*)&keT[(w*32 + ti*16 + (l&15))*72 + ks*32 + (l>>4)*8];
#pragma unroll
    for (int tj = 0; tj < 8; tj++){
      bf16x8 bf_ = *(const bf16x8*)&vT[(tj*16 + (l&15))*72 + ks*32 + (l>>4)*8];
#pragma unroll
      for (int ti = 0; ti < 2; ti++) acc[ti][tj] = MFMA(af[ti], bf_, acc[ti][tj]);
    }
  }
  size_t tbase = ((size_t)(b*8+kvh)*32 + c)*16384;
#pragma unroll
  for (int ti = 0; ti < 2; ti++)
#pragma unroll
    for (int tj = 0; tj < 8; tj++)
#pragma unroll
      for (int rr = 0; rr < 4; rr++){
        int d = w*32 + ti*16 + (l>>4)*4 + rr, e = tj*16 + (l&15);
        T[tbase + d*128 + e] = f2b(acc[ti][tj][rr]);
      }
}

// ---------------- phase B ----------------
__global__ __launch_bounds__(256) void k_phaseB(const u16* __restrict__ T, const float* __restrict__ Dv,
                                                u16* __restrict__ SP){
  __shared__ u16 sl[16*128];
  int es = blockIdx.x, kvh = blockIdx.y, b = blockIdx.z;
  int t = threadIdx.x;
  size_t bh = (size_t)(b*8 + kvh);
  float S[8] = {0,0,0,0,0,0,0,0};
  for (int c = 0; c < 32; c++){
#pragma unroll
    for (int r = 0; r < 8; r++){
      int idx = r*256 + t, d = idx>>4, el = idx&15;
      sl[el*128 + d] = f2b(S[r]);
    }
    __syncthreads();
    size_t spb = (bh*32 + c)*16384 + (size_t)es*2048;
    *(u16x8*)&SP[spb + t*8] = *(const u16x8*)&sl[t*8];
    size_t tb  = (bh*32 + c)*16384;
    size_t dvb = (bh*32 + c)*128;
#pragma unroll
    for (int r = 0; r < 8; r++){
      int idx = r*256 + t, d = idx>>4, el = idx&15;
      float tv = b2f(T[tb + d*128 + es*16 + el]);
      S[r] = S[r]*Dv[dvb + d] + tv;
    }
    __syncthreads();
  }
}

// ---------------- phase C ----------------
__global__ __launch_bounds__(256) void k_phaseC(const u16* __restrict__ QKV, const u16* __restrict__ eb,
                                                const u16* __restrict__ kd, const u16* __restrict__ SP,
                                                const float* __restrict__ gnw, u16* __restrict__ onrm){
  __shared__ u16 kl[64*128];
  __shared__ u16 sl[64*72];
  __shared__ u16 vT[128*72];
  int c = blockIdx.x, h = blockIdx.y, b = blockIdx.z;
  int kvh = h >> 1;
  int t = threadIdx.x, w = t>>6, l = t&63;
  int tok0 = b*2048 + c*64;
#pragma unroll
  for (int is = 0; is < 4; is++){
    int row = (t>>4) + is*16;
    int d0s = 8*((t&15) ^ (row&7));
    gload16(&kd[(size_t)(tok0+row)*1024 + kvh*128 + d0s], &kl[is*2048 + w*512]);
  }
  int d0v = (t&15)*8;
#pragma unroll
  for (int r = 0; r < 4; r++){
    int i = (t>>4) + r*16;
    u16x8 vv = *(const u16x8*)&QKV[(size_t)(tok0+i)*4096 + 3072 + kvh*128 + d0v];
#pragma unroll
    for (int jj = 0; jj < 8; jj++) vT[(d0v+jj)*72 + i] = vv[jj];
  }
  bf16x8 aq[4];
  {
    int i = w*16 + (l&15);
#pragma unroll
    for (int kt = 0; kt < 4; kt++){
      int dq = kt*32 + (l>>4)*8;
      u16x8 qv = *(const u16x8*)&QKV[(size_t)(tok0+i)*4096 + h*128 + dq];
      u16x8 ev = *(const u16x8*)&eb[(size_t)(tok0+i)*1024 + kvh*128 + dq];
      u16x8 o;
#pragma unroll
      for (int jj = 0; jj < 8; jj++) o[jj] = f2b(b2f(qv[jj]) * b2f(ev[jj]));
      aq[kt] = __builtin_bit_cast(bf16x8, o);
    }
  }
  __syncthreads();
  f32x4 accs[4] = {};
#pragma unroll
  for (int kt = 0; kt < 4; kt++){
#pragma unroll
    for (int jt = 0; jt < 4; jt++){
      int j = jt*16 + (l&15);
      int byte_ = j*256 + ((2*(kt*32 + (l>>4)*8)) ^ ((j&7)<<4));
      bf16x8 bk_ = *(const bf16x8*)((const char*)kl + byte_);
      accs[jt] = MFMA(aq[kt], bk_, accs[jt]);
    }
  }
#pragma unroll
  for (int jt = 0; jt < 4; jt++)
#pragma unroll
    for (int rr = 0; rr < 4; rr++){
      int i = w*16 + (l>>4)*4 + rr;
      int j = jt*16 + (l&15);
      sl[i*72 + j] = f2b((i >= j) ? accs[jt][rr] : 0.f);
    }
  f32x4 acco[8] = {};
  size_t spb = ((size_t)(b*8+kvh)*32 + c)*16384;
#pragma unroll
  for (int kt = 0; kt < 4; kt++){
#pragma unroll
    for (int et = 0; et < 8; et++){
      int e = et*16 + (l&15);
      int dd = kt*32 + (l>>4)*8;
      bf16x8 bs = *(const bf16x8*)&SP[spb + (size_t)e*128 + dd];
      acco[et] = MFMA(aq[kt], bs, acco[et]);
    }
  }
#pragma unroll
  for (int kt2 = 0; kt2 < 2; kt2++){
    int i = w*16 + (l&15);
    bf16x8 as = *(const bf16x8*)&sl[i*72 + kt2*32 + (l>>4)*8];
#pragma unroll
    for (int et = 0; et < 8; et++){
      bf16x8 bv_ = *(const bf16x8*)&vT[(et*16 + (l&15))*72 + kt2*32 + (l>>4)*8];
      acco[et] = MFMA(as, bv_, acco[et]);
    }
  }
  float gw[8];
#pragma unroll
  for (int et = 0; et < 8; et++) gw[et] = gnw[et*16 + (l&15)];
#pragma unroll
  for (int rr = 0; rr < 4; rr++){
    int i = w*16 + (l>>4)*4 + rr;
    float ss = 0.f;
#pragma unroll
    for (int et = 0; et < 8; et++){ float x = acco[et][rr]; ss += x*x; }
    ss += __shfl_xor(ss, 1); ss += __shfl_xor(ss, 2);
    ss += __shfl_xor(ss, 4); ss += __shfl_xor(ss, 8);
    float sc = rsqrtf(ss*(1.f/128.f) + 1e-5f);
#pragma unroll
    for (int et = 0; et < 8; et++){
      int e = et*16 + (l&15);
      onrm[(size_t)(tok0+i)*2048 + h*128 + e] = f2b(acco[et][rr]*sc*gw[et]);
    }
  }
}

extern "C" void kernel_launch(void* const* d_in, const int* in_sizes, int n_in,
                              void* d_out, int out_size, void* d_ws, size_t ws_size,
                              hipStream_t stream){
  (void)in_sizes; (void)n_in; (void)out_size; (void)ws_size;
  const float* h   = (const float*)d_in[0];
  const float* Wq  = (const float*)d_in[1];
  const float* bq  = (const float*)d_in[2];
  const float* Wk  = (const float*)d_in[3];
  const float* bk  = (const float*)d_in[4];
  const float* Wv  = (const float*)d_in[5];
  const float* bv  = (const float*)d_in[6];
  const float* Wg1 = (const float*)d_in[7];
  const float* Wg2 = (const float*)d_in[8];
  const float* bg2 = (const float*)d_in[9];
  const float* gnw = (const float*)d_in[10];
  const float* Wo  = (const float*)d_in[11];
  float* out = (float*)d_out;
  char* ws = (char*)d_ws;
  u16*   hb   = (u16*)  (ws + OFF_HB);
  u16*   wct  = (u16*)  (ws + OFF_WCT);
  u16*   wot  = (u16*)  (ws + OFF_WOT);
  u16*   qkv  = (u16*)  (ws + OFF_QKV);
  float* gbuf = (float*)(ws + OFF_G);
  u16*   ebuf = (u16*)  (ws + OFF_EB);
  u16*   kdb  = (u16*)  (ws + OFF_KD);
  u16*   Tb   = (u16*)  (ws + OFF_T);
  u16*   wtilT= (u16*)  (ws + OFF_T);   // overlays T; consumed by gemmG before phaseA writes T
  float* Dvb  = (float*)(ws + OFF_DV);
  u16*   SPb  = (u16*)  (ws + OFF_SP);
  u16*   onb  = (u16*)  (ws + OFF_ON);

  k_conv_h<<<2048, 256, 0, stream>>>(h, hb);
  k_transpose<<<dim3(32,32), 256, 0, stream>>>(Wq,  wct, 2048, 2048,    0, 2048);
  k_transpose<<<dim3(16,32), 256, 0, stream>>>(Wk,  wct, 2048, 1024, 2048, 2048);
  k_transpose<<<dim3(16,32), 256, 0, stream>>>(Wv,  wct, 2048, 1024, 3072, 2048);
  k_transpose<<<dim3(32,32), 256, 0, stream>>>(Wo,  wot, 2048, 2048,    0, 2048);
  k_wtilde<<<128, 256, 0, stream>>>(Wg1, Wg2, wtilT);
  gemm256<256,0><<<256, 512, 0, stream>>>(hb, wct, qkv, nullptr, bq, bk, bv);
  gemmG<<<256, 256, 0, stream>>>(hb, wtilT, gbuf, bg2);
  k_phaseA<<<dim3(32,8,2), 256, 0, stream>>>(gbuf, qkv, ebuf, kdb, Tb, Dvb);
  k_phaseB<<<dim3(8,8,2), 256, 0, stream>>>(Tb, Dvb, SPb);
  k_phaseC<<<dim3(32,16,2), 256, 0, stream>>>(qkv, ebuf, kdb, SPb, gnw, onb);
  gemm256<128,1><<<256, 512, 0, stream>>>(onb, wot, nullptr, out, nullptr, nullptr, nullptr);
}

// Round 10
// 422.966 us; speedup vs baseline: 1.5354x; 1.1249x over previous
//
#include <hip/hip_runtime.h>

typedef unsigned short u16;
typedef u16 u16x8 __attribute__((ext_vector_type(8)));
typedef u16 u16x4 __attribute__((ext_vector_type(4)));
typedef __bf16 bf16x8 __attribute__((ext_vector_type(8)));
typedef float f32x4 __attribute__((ext_vector_type(4)));

#define DEVI static __device__ __forceinline__

DEVI float b2f(u16 u){ union { unsigned u; float f; } c; c.u = ((unsigned)u) << 16; return c.f; }
DEVI u16 f2b(float f){ union { float f; unsigned u; } c; c.f = f;
  unsigned r = c.u + 0x7fffu + ((c.u >> 16) & 1u); return (u16)(r >> 16); }
DEVI void gload16(const void* g, void* l){
  __builtin_amdgcn_global_load_lds((const __attribute__((address_space(1))) void*)g,
                                   (__attribute__((address_space(3))) void*)l, 16, 0, 0);
}
DEVI f32x4 MFMA(bf16x8 a, bf16x8 b, f32x4 c){
  return __builtin_amdgcn_mfma_f32_16x16x32_bf16(a, b, c, 0, 0, 0);
}

// B=2, L=2048, HID=2048, H=16, HKV=8, D=128, CHUNK=64, NC=32, TOK=4096
constexpr size_t OFF_HB  = 0;                                   // h bf16 [4096][2048]
constexpr size_t OFF_WCT = OFF_HB  + (size_t)4096*2048*2;       // WcatT bf16 (Wq|Wk|Wv)^T [4096][2048]
constexpr size_t OFF_WOT = OFF_WCT + (size_t)4224*2048*2;       // WoT bf16 [2048][2048]
constexpr size_t OFF_QKV = OFF_WOT + (size_t)2048*2048*2;       // QKV bf16 [4096][4096]
constexpr size_t OFF_G1  = OFF_QKV + (size_t)4096*4096*2;       // (unused)
constexpr size_t OFF_G   = OFF_G1  + (size_t)4096*16*4;         // g f32 [4096][1024] raw logits
constexpr size_t OFF_EB  = OFF_G   + (size_t)4096*1024*4;       // exp(b) bf16 [4096][1024]
constexpr size_t OFF_KD  = OFF_EB  + (size_t)4096*1024*2;       // k*exp(-b) bf16 [4096][1024]
constexpr size_t OFF_T   = OFF_KD  + (size_t)4096*1024*2;       // T^T bf16 [2][8][32][128 e][128 d]; wtilT overlays
constexpr size_t OFF_DV  = OFF_T   + (size_t)2*8*32*128*128*2;  // Dvec f32 [2][8][32][128]
constexpr size_t OFF_SP  = OFF_DV  + (size_t)2*8*32*128*4;      // S_prefix bf16 [2][8][32][128 e][128 d]
constexpr size_t OFF_ON  = OFF_SP  + (size_t)2*8*32*128*128*2;  // o_normed bf16 [4096][2048]

// ---------------- conversion ----------------
__global__ __launch_bounds__(256) void k_conv_h(const float* __restrict__ h, u16* __restrict__ hb){
  int idx = blockIdx.x*256 + threadIdx.x, stride = gridDim.x*256;
  for (int i = idx; i < 4096*2048/4; i += stride){
    float4 v = ((const float4*)h)[i];
    u16x4 o; o[0]=f2b(v.x); o[1]=f2b(v.y); o[2]=f2b(v.z); o[3]=f2b(v.w);
    ((u16x4*)hb)[i] = o;
  }
}

// dst[(rowOff+n)*pitch + k] = bf16(src[k][n])
__global__ __launch_bounds__(256) void k_transpose(const float* __restrict__ src, u16* __restrict__ dst,
                                                   int K, int N, int rowOff, int pitch){
  __shared__ float tile[64][65];
  int kb = blockIdx.y*64, nb = blockIdx.x*64;
  int t = threadIdx.x, x = t & 63, y0 = t >> 6;
#pragma unroll
  for (int i = 0; i < 16; i++){
    int y = y0 + i*4, k = kb + y, n = nb + x;
    tile[y][x] = (n < N) ? src[(size_t)k*N + n] : 0.f;
  }
  __syncthreads();
#pragma unroll
  for (int i = 0; i < 16; i++){
    int y = y0 + i*4, n = nb + y, k = kb + x;
    if (n < N) dst[(size_t)(rowOff + n)*pitch + k] = f2b(tile[x][y]);
  }
}

// ---------------- wtilT[c][r] = bf16( sum_j Wg1[r][j] * Wg2[j][c] ) ----------------
__global__ __launch_bounds__(256) void k_wtilde(const float* __restrict__ Wg1, const float* __restrict__ Wg2,
                                                u16* __restrict__ wt){
  __shared__ float w2s[16*8];
  int c0 = blockIdx.x*8, t = threadIdx.x;
  if (t < 128){ int j = t>>3, cc = t&7; w2s[j*8+cc] = Wg2[j*1024 + c0 + cc]; }
  __syncthreads();
  int r0 = t*8;
#pragma unroll
  for (int half = 0; half < 2; half++){
    float rowv[4][16];
#pragma unroll
    for (int u = 0; u < 4; u++)
#pragma unroll
      for (int j4 = 0; j4 < 4; j4++)
        *(float4*)&rowv[u][j4*4] = *(const float4*)&Wg1[(size_t)(r0 + half*4 + u)*16 + j4*4];
#pragma unroll
    for (int cc = 0; cc < 8; cc++){
      u16x4 o;
#pragma unroll
      for (int u = 0; u < 4; u++){
        float s = 0.f;
#pragma unroll
        for (int j = 0; j < 16; j++) s += rowv[u][j]*w2s[j*8+cc];
        o[u] = f2b(s);
      }
      *(u16x4*)&wt[(size_t)(c0+cc)*2048 + r0 + half*4] = o;
    }
  }
}

// ---------------- m97-style 128x128 GEMM: 2 buffers, 32KB LDS, 4 blocks/CU, 1 barrier/K-step ----------------
// C[m][n] = sum_k A[m][k]*Bt[n][k], K=2048, BK=32, 4 waves (2x2), wave tile 64x64.
// LDS: [row][4 granules 16B], slot g' = g ^ ((r>>1)&3) -> 0 bank conflicts (verified r6-r8).
// MODE 0: QKV epilogue bf16 N=4096 (grid 1024). MODE 1: fp32 out pitch 2048 (grid 512).
// MODE 2: gate logits f32 +bg2, pitch 1024 (grid 256).
template<int MODE>
__global__ __launch_bounds__(256, 4) void gemm128(const u16* __restrict__ A, const u16* __restrict__ Bt,
                                                  u16* __restrict__ Cq, float* __restrict__ Cf,
                                                  const float* __restrict__ bq, const float* __restrict__ bk,
                                                  const float* __restrict__ bv, const float* __restrict__ bg2){
  constexpr int NT = 64;
  constexpr int NTN = (MODE==0) ? 32 : (MODE==1) ? 16 : 8;
  constexpr int CPX = (MODE==0) ? 128 : (MODE==1) ? 64 : 32;   // grid/8 (grid%8==0 -> bijective)
  __shared__ u16 sA[2*128*32];
  __shared__ u16 sB[2*128*32];
  int id = blockIdx.x;
  int swz = (id & 7)*CPX + (id >> 3);
  int mt = swz / NTN, nt = swz % NTN;
  int t = threadIdx.x, w = t >> 6, l = t & 63;
  int wr = w >> 1, wc = w & 1;
  int mRow0 = mt*128, nCol0 = nt*128;
  const u16* srcA[2]; const u16* srcB[2];
#pragma unroll
  for (int i = 0; i < 2; i++){
    int S = t + i*256, r = S>>2, g = (S&3) ^ ((r>>1)&3);
    srcA[i] = A + (size_t)(mRow0 + r)*2048 + g*8;
    srcB[i] = Bt + (size_t)(nCol0 + r)*2048 + g*8;
  }
  auto ISSUE = [&](int T){
    int buf = T & 1;
    u16* dA = sA + buf*4096;
    u16* dB = sB + buf*4096;
#pragma unroll
    for (int i = 0; i < 2; i++) gload16(srcA[i] + T*32, dA + (i*256 + w*64)*8);
#pragma unroll
    for (int i = 0; i < 2; i++) gload16(srcB[i] + T*32, dB + (i*256 + w*64)*8);
  };
  f32x4 acc[4][4] = {};
  ISSUE(0);
  for (int T = 0; T < NT; ++T){
    __syncthreads();                      // drains vmcnt: tile T landed; prev readers done
    if (T + 1 < NT) ISSUE(T + 1);         // prefetch next into other buffer (hidden under MFMA)
    const u16* bufA = sA + (T&1)*4096;
    const u16* bufB = sB + (T&1)*4096;
    bf16x8 bfr[4], afr[4];
#pragma unroll
    for (int ni = 0; ni < 4; ni++){
      int r = wc*64 + ni*16 + (l&15);
      int p = (l>>4) ^ ((r>>1)&3);
      bfr[ni] = *(const bf16x8*)&bufB[(r*4 + p)*8];
    }
#pragma unroll
    for (int mi = 0; mi < 4; mi++){
      int r = wr*64 + mi*16 + (l&15);
      int p = (l>>4) ^ ((r>>1)&3);
      afr[mi] = *(const bf16x8*)&bufA[(r*4 + p)*8];
    }
    __builtin_amdgcn_s_setprio(1);
#pragma unroll
    for (int mi = 0; mi < 4; mi++)
#pragma unroll
      for (int ni = 0; ni < 4; ni++)
        acc[mi][ni] = MFMA(afr[mi], bfr[ni], acc[mi][ni]);
    __builtin_amdgcn_s_setprio(0);
  }
  // epilogue (each block is a single output kind)
  int iLoc = (l>>4)*4, jc = l & 15;
  if (MODE == 0){
    int kind = (nt < 16) ? 0 : (nt < 24) ? 1 : 2;
#pragma unroll
    for (int ni = 0; ni < 4; ni++){
      int n = nCol0 + wc*64 + ni*16 + jc;
      float bias = (kind == 0) ? bq[n] : (kind == 1) ? bk[n - 2048] : bv[n - 3072];
#pragma unroll
      for (int mi = 0; mi < 4; mi++){
        int m = mRow0 + wr*64 + mi*16 + iLoc;
#pragma unroll
        for (int rr = 0; rr < 4; rr++){
          float x = acc[mi][ni][rr] + bias;
          int row = m + rr;
          if (kind == 0)      Cq[(size_t)row*4096 + n] = f2b(fmaxf(x, 0.f) * 0.08838834764831845f);
          else if (kind == 1) Cq[(size_t)row*4096 + n] = f2b(fmaxf(x, 0.f));
          else                Cq[(size_t)row*4096 + n] = f2b(x);
        }
      }
    }
  } else if (MODE == 1){
#pragma unroll
    for (int ni = 0; ni < 4; ni++){
      int n = nCol0 + wc*64 + ni*16 + jc;
#pragma unroll
      for (int mi = 0; mi < 4; mi++){
        int m = mRow0 + wr*64 + mi*16 + iLoc;
#pragma unroll
        for (int rr = 0; rr < 4; rr++) Cf[(size_t)(m+rr)*2048 + n] = acc[mi][ni][rr];
      }
    }
  } else {
#pragma unroll
    for (int ni = 0; ni < 4; ni++){
      int n = nCol0 + wc*64 + ni*16 + jc;
      float bias = bg2[n];
#pragma unroll
      for (int mi = 0; mi < 4; mi++){
        int m = mRow0 + wr*64 + mi*16 + iLoc;
#pragma unroll
        for (int rr = 0; rr < 4; rr++) Cf[(size_t)(m+rr)*1024 + n] = acc[mi][ni][rr] + bias;
      }
    }
  }
}

// ---------------- phase A: cumsum gates, eb, kd, T^T = v^T @ kend (logsigmoid fused) ----------------
__global__ __launch_bounds__(256) void k_phaseA(const float* __restrict__ g, const u16* __restrict__ QKV,
                                                u16* __restrict__ eb, u16* __restrict__ kd,
                                                u16* __restrict__ T, float* __restrict__ Dv){
  __shared__ float gb[64*128];
  __shared__ u16 keT[128*72];
  __shared__ u16 vT [128*72];
  int c = blockIdx.x, kvh = blockIdx.y, b = blockIdx.z;
  int t = threadIdx.x;
  int tok0 = b*2048 + c*64;
#pragma unroll
  for (int r = 0; r < 8; r++){
    int idx4 = r*256 + t;
    int i = idx4 >> 5, c4 = idx4 & 31;
    float4 v = *(const float4*)&g[(size_t)(tok0+i)*1024 + kvh*128 + c4*4];
    float4 o;
    o.x = (fminf(v.x,0.f) - log1pf(expf(-fabsf(v.x)))) * 0.0625f;
    o.y = (fminf(v.y,0.f) - log1pf(expf(-fabsf(v.y)))) * 0.0625f;
    o.z = (fminf(v.z,0.f) - log1pf(expf(-fabsf(v.z)))) * 0.0625f;
    o.w = (fminf(v.w,0.f) - log1pf(expf(-fabsf(v.w)))) * 0.0625f;
    ((float4*)gb)[i*32 + c4] = o;
  }
  __syncthreads();
  if (t < 128){
    float run = 0.f;
    for (int i = 0; i < 64; i++){ run += gb[i*128 + t]; gb[i*128 + t] = run; }
    Dv[((size_t)(b*8+kvh)*32 + c)*128 + t] = expf(run);
  }
  __syncthreads();
  int d0 = (t&15)*8;
  float blast[8];
#pragma unroll
  for (int j = 0; j < 8; j++) blast[j] = gb[63*128 + d0 + j];
#pragma unroll
  for (int r = 0; r < 4; r++){
    int i = (t>>4) + r*16;
    u16x8 kv_ = *(const u16x8*)&QKV[(size_t)(tok0+i)*4096 + 2048 + kvh*128 + d0];
    u16x8 vv  = *(const u16x8*)&QKV[(size_t)(tok0+i)*4096 + 3072 + kvh*128 + d0];
    u16x8 ebv, kdv;
#pragma unroll
    for (int j = 0; j < 8; j++){
      float bcur = gb[i*128 + d0 + j];
      float kf = b2f(kv_[j]);
      ebv[j] = f2b(expf(bcur));
      kdv[j] = f2b(kf * expf(-bcur));
      keT[(d0+j)*72 + i] = f2b(kf * expf(blast[j] - bcur));
      vT [(d0+j)*72 + i] = vv[j];
    }
    *(u16x8*)&eb[(size_t)(tok0+i)*1024 + kvh*128 + d0] = ebv;
    *(u16x8*)&kd[(size_t)(tok0+i)*1024 + kvh*128 + d0] = kdv;
  }
  __syncthreads();
  int w = t>>6, l = t&63;
  // T^T[e][d]: A-operand = v^T rows (e), B-operand = kend^T rows (d)
  f32x4 acc[2][8] = {};
#pragma unroll
  for (int ks = 0; ks < 2; ks++){
    bf16x8 af[2];
#pragma unroll
    for (int te = 0; te < 2; te++)
      af[te] = *(const bf16x8*)&vT[(w*32 + te*16 + (l&15))*72 + ks*32 + (l>>4)*8];
#pragma unroll
    for (int td = 0; td < 8; td++){
      bf16x8 bf_ = *(const bf16x8*)&keT[(td*16 + (l&15))*72 + ks*32 + (l>>4)*8];
#pragma unroll
      for (int te = 0; te < 2; te++) acc[te][td] = MFMA(af[te], bf_, acc[te][td]);
    }
  }
  size_t tbase = ((size_t)(b*8+kvh)*32 + c)*16384;
#pragma unroll
  for (int te = 0; te < 2; te++)
#pragma unroll
    for (int td = 0; td < 8; td++)
#pragma unroll
      for (int rr = 0; rr < 4; rr++){
        int e = w*32 + te*16 + (l>>4)*4 + rr, d = td*16 + (l&15);
        T[tbase + e*128 + d] = f2b(acc[te][td][rr]);
      }
}

// ---------------- phase B: elementwise scan over chunks (no LDS, no barriers) ----------------
// S[e][d] : SP[c] = S ; S = S*Dv[c][d] + T^T[c][e][d]
__global__ __launch_bounds__(256) void k_phaseB(const u16* __restrict__ T, const float* __restrict__ Dv,
                                                u16* __restrict__ SP){
  int kvh = blockIdx.y, b = blockIdx.z;
  int t = threadIdx.x;
  int e = blockIdx.x*16 + (t >> 4);
  int d0 = (t & 15)*8;
  size_t base = ((size_t)(b*8 + kvh)*32)*16384 + (size_t)e*128 + d0;
  size_t dvb  = ((size_t)(b*8 + kvh)*32)*128 + d0;
  float S[8] = {0,0,0,0,0,0,0,0};
  for (int c = 0; c < 32; c++){
    u16x8 tv = *(const u16x8*)&T[base + (size_t)c*16384];
    float4 dva = *(const float4*)&Dv[dvb + (size_t)c*128];
    float4 dvbv = *(const float4*)&Dv[dvb + (size_t)c*128 + 4];
    u16x8 o;
#pragma unroll
    for (int j = 0; j < 8; j++) o[j] = f2b(S[j]);
    *(u16x8*)&SP[base + (size_t)c*16384] = o;
    float dv[8] = {dva.x, dva.y, dva.z, dva.w, dvbv.x, dvbv.y, dvbv.z, dvbv.w};
#pragma unroll
    for (int j = 0; j < 8; j++) S[j] = S[j]*dv[j] + b2f(tv[j]);
  }
}

// ---------------- phase C ----------------
__global__ __launch_bounds__(256) void k_phaseC(const u16* __restrict__ QKV, const u16* __restrict__ eb,
                                                const u16* __restrict__ kd, const u16* __restrict__ SP,
                                                const float* __restrict__ gnw, u16* __restrict__ onrm){
  __shared__ u16 kl[64*128];
  __shared__ u16 sl[64*72];
  __shared__ u16 vT[128*72];
  int c = blockIdx.x, h = blockIdx.y, b = blockIdx.z;
  int kvh = h >> 1;
  int t = threadIdx.x, w = t>>6, l = t&63;
  int tok0 = b*2048 + c*64;
#pragma unroll
  for (int is = 0; is < 4; is++){
    int row = (t>>4) + is*16;
    int d0s = 8*((t&15) ^ (row&7));
    gload16(&kd[(size_t)(tok0+row)*1024 + kvh*128 + d0s], &kl[is*2048 + w*512]);
  }
  int d0v = (t&15)*8;
#pragma unroll
  for (int r = 0; r < 4; r++){
    int i = (t>>4) + r*16;
    u16x8 vv = *(const u16x8*)&QKV[(size_t)(tok0+i)*4096 + 3072 + kvh*128 + d0v];
#pragma unroll
    for (int jj = 0; jj < 8; jj++) vT[(d0v+jj)*72 + i] = vv[jj];
  }
  bf16x8 aq[4];
  {
    int i = w*16 + (l&15);
#pragma unroll
    for (int kt = 0; kt < 4; kt++){
      int dq = kt*32 + (l>>4)*8;
      u16x8 qv = *(const u16x8*)&QKV[(size_t)(tok0+i)*4096 + h*128 + dq];
      u16x8 ev = *(const u16x8*)&eb[(size_t)(tok0+i)*1024 + kvh*128 + dq];
      u16x8 o;
#pragma unroll
      for (int jj = 0; jj < 8; jj++) o[jj] = f2b(b2f(qv[jj]) * b2f(ev[jj]));
      aq[kt] = __builtin_bit_cast(bf16x8, o);
    }
  }
  __syncthreads();
  f32x4 accs[4] = {};
#pragma unroll
  for (int kt = 0; kt < 4; kt++){
#pragma unroll
    for (int jt = 0; jt < 4; jt++){
      int j = jt*16 + (l&15);
      int byte_ = j*256 + ((2*(kt*32 + (l>>4)*8)) ^ ((j&7)<<4));
      bf16x8 bk_ = *(const bf16x8*)((const char*)kl + byte_);
      accs[jt] = MFMA(aq[kt], bk_, accs[jt]);
    }
  }
#pragma unroll
  for (int jt = 0; jt < 4; jt++)
#pragma unroll
    for (int rr = 0; rr < 4; rr++){
      int i = w*16 + (l>>4)*4 + rr;
      int j = jt*16 + (l&15);
      sl[i*72 + j] = f2b((i >= j) ? accs[jt][rr] : 0.f);
    }
  f32x4 acco[8] = {};
  size_t spb = ((size_t)(b*8+kvh)*32 + c)*16384;
#pragma unroll
  for (int kt = 0; kt < 4; kt++){
#pragma unroll
    for (int et = 0; et < 8; et++){
      int e = et*16 + (l&15);
      int dd = kt*32 + (l>>4)*8;
      bf16x8 bs = *(const bf16x8*)&SP[spb + (size_t)e*128 + dd];
      acco[et] = MFMA(aq[kt], bs, acco[et]);
    }
  }
#pragma unroll
  for (int kt2 = 0; kt2 < 2; kt2++){
    int i = w*16 + (l&15);
    bf16x8 as = *(const bf16x8*)&sl[i*72 + kt2*32 + (l>>4)*8];
#pragma unroll
    for (int et = 0; et < 8; et++){
      bf16x8 bv_ = *(const bf16x8*)&vT[(et*16 + (l&15))*72 + kt2*32 + (l>>4)*8];
      acco[et] = MFMA(as, bv_, acco[et]);
    }
  }
  float gw[8];
#pragma unroll
  for (int et = 0; et < 8; et++) gw[et] = gnw[et*16 + (l&15)];
#pragma unroll
  for (int rr = 0; rr < 4; rr++){
    int i = w*16 + (l>>4)*4 + rr;
    float ss = 0.f;
#pragma unroll
    for (int et = 0; et < 8; et++){ float x = acco[et][rr]; ss += x*x; }
    ss += __shfl_xor(ss, 1); ss += __shfl_xor(ss, 2);
    ss += __shfl_xor(ss, 4); ss += __shfl_xor(ss, 8);
    float sc = rsqrtf(ss*(1.f/128.f) + 1e-5f);
#pragma unroll
    for (int et = 0; et < 8; et++){
      int e = et*16 + (l&15);
      onrm[(size_t)(tok0+i)*2048 + h*128 + e] = f2b(acco[et][rr]*sc*gw[et]);
    }
  }
}

extern "C" void kernel_launch(void* const* d_in, const int* in_sizes, int n_in,
                              void* d_out, int out_size, void* d_ws, size_t ws_size,
                              hipStream_t stream){
  (void)in_sizes; (void)n_in; (void)out_size; (void)ws_size;
  const float* h   = (const float*)d_in[0];
  const float* Wq  = (const float*)d_in[1];
  const float* bq  = (const float*)d_in[2];
  const float* Wk  = (const float*)d_in[3];
  const float* bk  = (const float*)d_in[4];
  const float* Wv  = (const float*)d_in[5];
  const float* bv  = (const float*)d_in[6];
  const float* Wg1 = (const float*)d_in[7];
  const float* Wg2 = (const float*)d_in[8];
  const float* bg2 = (const float*)d_in[9];
  const float* gnw = (const float*)d_in[10];
  const float* Wo  = (const float*)d_in[11];
  float* out = (float*)d_out;
  char* ws = (char*)d_ws;
  u16*   hb   = (u16*)  (ws + OFF_HB);
  u16*   wct  = (u16*)  (ws + OFF_WCT);
  u16*   wot  = (u16*)  (ws + OFF_WOT);
  u16*   qkv  = (u16*)  (ws + OFF_QKV);
  float* gbuf = (float*)(ws + OFF_G);
  u16*   ebuf = (u16*)  (ws + OFF_EB);
  u16*   kdb  = (u16*)  (ws + OFF_KD);
  u16*   Tb   = (u16*)  (ws + OFF_T);
  u16*   wtilT= (u16*)  (ws + OFF_T);   // overlays T; consumed by gemm128<2> before phaseA writes T
  float* Dvb  = (float*)(ws + OFF_DV);
  u16*   SPb  = (u16*)  (ws + OFF_SP);
  u16*   onb  = (u16*)  (ws + OFF_ON);

  k_conv_h<<<2048, 256, 0, stream>>>(h, hb);
  k_transpose<<<dim3(32,32), 256, 0, stream>>>(Wq,  wct, 2048, 2048,    0, 2048);
  k_transpose<<<dim3(16,32), 256, 0, stream>>>(Wk,  wct, 2048, 1024, 2048, 2048);
  k_transpose<<<dim3(16,32), 256, 0, stream>>>(Wv,  wct, 2048, 1024, 3072, 2048);
  k_transpose<<<dim3(32,32), 256, 0, stream>>>(Wo,  wot, 2048, 2048,    0, 2048);
  k_wtilde<<<128, 256, 0, stream>>>(Wg1, Wg2, wtilT);
  gemm128<0><<<1024, 256, 0, stream>>>(hb, wct, qkv, nullptr, bq, bk, bv, nullptr);
  gemm128<2><<<256, 256, 0, stream>>>(hb, wtilT, nullptr, gbuf, nullptr, nullptr, nullptr, bg2);
  k_phaseA<<<dim3(32,8,2), 256, 0, stream>>>(gbuf, qkv, ebuf, kdb, Tb, Dvb);
  k_phaseB<<<dim3(8,8,2), 256, 0, stream>>>(Tb, Dvb, SPb);
  k_phaseC<<<dim3(32,16,2), 256, 0, stream>>>(qkv, ebuf, kdb, SPb, gnw, onb);
  gemm128<1><<<512, 256, 0, stream>>>(onb, wot, nullptr, out, nullptr, nullptr, nullptr, nullptr);
}

// Round 11
// 406.004 us; speedup vs baseline: 1.5996x; 1.0418x over previous
//
#include <hip/hip_runtime.h>

typedef unsigned short u16;
typedef u16 u16x8 __attribute__((ext_vector_type(8)));
typedef u16 u16x4 __attribute__((ext_vector_type(4)));
typedef __bf16 bf16x8 __attribute__((ext_vector_type(8)));
typedef float f32x4 __attribute__((ext_vector_type(4)));

#define DEVI static __device__ __forceinline__

DEVI float b2f(u16 u){ union { unsigned u; float f; } c; c.u = ((unsigned)u) << 16; return c.f; }
DEVI u16 f2b(float f){ union { float f; unsigned u; } c; c.f = f;
  unsigned r = c.u + 0x7fffu + ((c.u >> 16) & 1u); return (u16)(r >> 16); }
DEVI void gload16(const void* g, void* l){
  __builtin_amdgcn_global_load_lds((const __attribute__((address_space(1))) void*)g,
                                   (__attribute__((address_space(3))) void*)l, 16, 0, 0);
}
DEVI f32x4 MFMA(bf16x8 a, bf16x8 b, f32x4 c){
  return __builtin_amdgcn_mfma_f32_16x16x32_bf16(a, b, c, 0, 0, 0);
}

// B=2, L=2048, HID=2048, H=16, HKV=8, D=128, CHUNK=64, NC=32, TOK=4096
constexpr size_t OFF_HB  = 0;                                   // h bf16 [4096][2048]
constexpr size_t OFF_WCT = OFF_HB  + (size_t)4096*2048*2;       // WcatT bf16 (Wq|Wk|Wv)^T [4096][2048]
constexpr size_t OFF_WOT = OFF_WCT + (size_t)4224*2048*2;       // WoT bf16 [2048][2048]
constexpr size_t OFF_QKV = OFF_WOT + (size_t)2048*2048*2;       // QKV bf16 [4096][4096]
constexpr size_t OFF_G1  = OFF_QKV + (size_t)4096*4096*2;       // (unused)
constexpr size_t OFF_G   = OFF_G1  + (size_t)4096*16*4;         // g f32 [4096][1024] raw logits
constexpr size_t OFF_EB  = OFF_G   + (size_t)4096*1024*4;       // exp(b) bf16 [4096][1024]
constexpr size_t OFF_KD  = OFF_EB  + (size_t)4096*1024*2;       // k*exp(-b) bf16 [4096][1024]
constexpr size_t OFF_T   = OFF_KD  + (size_t)4096*1024*2;       // T^T bf16 [2][8][32][128 e][128 d]
constexpr size_t OFF_DV  = OFF_T   + (size_t)2*8*32*128*128*2;  // Dvec f32 [2][8][32][128]
constexpr size_t OFF_SP  = OFF_DV  + (size_t)2*8*32*128*4;      // S_prefix bf16 [2][8][32][128 e][128 d]
constexpr size_t OFF_ON  = OFF_SP  + (size_t)2*8*32*128*128*2;  // o_normed bf16 [4096][2048]
constexpr size_t OFF_WTL = OFF_ON  + (size_t)4096*2048*2;       // wtilT bf16 [1024][2048]

// ---------------- fused prep: h->bf16, 4 weight transposes, wtilde ----------------
// grid 5248 x 256
__global__ __launch_bounds__(256) void k_prep(const float* __restrict__ h, u16* __restrict__ hb,
                                              const float* __restrict__ Wq, const float* __restrict__ Wk,
                                              const float* __restrict__ Wv, const float* __restrict__ Wo,
                                              u16* __restrict__ wct, u16* __restrict__ wot,
                                              const float* __restrict__ Wg1, const float* __restrict__ Wg2,
                                              u16* __restrict__ wt){
  __shared__ float tile[64][65];
  int id = blockIdx.x, t = threadIdx.x;
  if (id < 2048){
    int idx = id*256 + t;
    for (int i = idx; i < 4096*2048/4; i += 2048*256){
      float4 v = ((const float4*)h)[i];
      u16x4 o; o[0]=f2b(v.x); o[1]=f2b(v.y); o[2]=f2b(v.z); o[3]=f2b(v.w);
      ((u16x4*)hb)[i] = o;
    }
    return;
  }
  if (id < 5120){
    const float* src; u16* dst; int N, rowOff, bx, by;
    if (id < 3072){ int lo = id-2048; src = Wq; dst = wct; N = 2048; rowOff = 0;    bx = lo&31; by = lo>>5; }
    else if (id < 3584){ int lo = id-3072; src = Wk; dst = wct; N = 1024; rowOff = 2048; bx = lo&15; by = lo>>4; }
    else if (id < 4096){ int lo = id-3584; src = Wv; dst = wct; N = 1024; rowOff = 3072; bx = lo&15; by = lo>>4; }
    else { int lo = id-4096; src = Wo; dst = wot; N = 2048; rowOff = 0; bx = lo&31; by = lo>>5; }
    int kb = by*64, nb = bx*64;
    int x = t & 63, y0 = t >> 6;
#pragma unroll
    for (int i = 0; i < 16; i++){
      int y = y0 + i*4;
      tile[y][x] = src[(size_t)(kb + y)*N + nb + x];
    }
    __syncthreads();
#pragma unroll
    for (int i = 0; i < 16; i++){
      int y = y0 + i*4;
      dst[(size_t)(rowOff + nb + y)*2048 + kb + x] = f2b(tile[x][y]);
    }
    return;
  }
  // wtilde: wt[c][r] = bf16(sum_j Wg1[r][j]*Wg2[j][c]) ; 128 blocks x 8 cols
  __shared__ float w2s[16*8];
  int c0 = (id - 5120)*8;
  if (t < 128){ int j = t>>3, cc = t&7; w2s[j*8+cc] = Wg2[j*1024 + c0 + cc]; }
  __syncthreads();
  int r0 = t*8;
#pragma unroll
  for (int half = 0; half < 2; half++){
    float rowv[4][16];
#pragma unroll
    for (int u = 0; u < 4; u++)
#pragma unroll
      for (int j4 = 0; j4 < 4; j4++)
        *(float4*)&rowv[u][j4*4] = *(const float4*)&Wg1[(size_t)(r0 + half*4 + u)*16 + j4*4];
#pragma unroll
    for (int cc = 0; cc < 8; cc++){
      u16x4 o;
#pragma unroll
      for (int u = 0; u < 4; u++){
        float s = 0.f;
#pragma unroll
        for (int j = 0; j < 16; j++) s += rowv[u][j]*w2s[j*8+cc];
        o[u] = f2b(s);
      }
      *(u16x4*)&wt[(size_t)(c0+cc)*2048 + r0 + half*4] = o;
    }
  }
}

// ---------------- m97-style 128x128 GEMM (proven r10) ----------------
// MODE 0: fused QKV+gate, N=5120 (grid 1280): nt<32 -> QKV bf16; nt>=32 -> gate logits f32.
// MODE 1: fp32 out pitch 2048 (grid 512).
template<int MODE>
__global__ __launch_bounds__(256, 4) void gemm128(const u16* __restrict__ A, const u16* __restrict__ Bt,
                                                  const u16* __restrict__ BtHi,
                                                  u16* __restrict__ Cq, float* __restrict__ Cf,
                                                  const float* __restrict__ bq, const float* __restrict__ bk,
                                                  const float* __restrict__ bv, const float* __restrict__ bg2){
  constexpr int NT = 64;
  constexpr int NTN = (MODE==0) ? 40 : 16;
  constexpr int CPX = (MODE==0) ? 160 : 64;    // grid/8, bijective
  __shared__ u16 sA[2*128*32];
  __shared__ u16 sB[2*128*32];
  int id = blockIdx.x;
  int swz = (id & 7)*CPX + (id >> 3);
  int mt = swz / NTN, nt = swz % NTN;
  int t = threadIdx.x, w = t >> 6, l = t & 63;
  int wr = w >> 1, wc = w & 1;
  int mRow0 = mt*128, nCol0 = nt*128;
  const u16* Bbase = (MODE==0 && nCol0 >= 4096) ? (BtHi + (size_t)(nCol0-4096)*2048)
                                                : (Bt + (size_t)nCol0*2048);
  const u16* srcA[2]; const u16* srcB[2];
#pragma unroll
  for (int i = 0; i < 2; i++){
    int S = t + i*256, r = S>>2, g = (S&3) ^ ((r>>1)&3);
    srcA[i] = A + (size_t)(mRow0 + r)*2048 + g*8;
    srcB[i] = Bbase + (size_t)r*2048 + g*8;
  }
  auto ISSUE = [&](int T){
    int buf = T & 1;
    u16* dA = sA + buf*4096;
    u16* dB = sB + buf*4096;
#pragma unroll
    for (int i = 0; i < 2; i++) gload16(srcA[i] + T*32, dA + (i*256 + w*64)*8);
#pragma unroll
    for (int i = 0; i < 2; i++) gload16(srcB[i] + T*32, dB + (i*256 + w*64)*8);
  };
  f32x4 acc[4][4] = {};
  ISSUE(0);
  for (int T = 0; T < NT; ++T){
    __syncthreads();
    if (T + 1 < NT) ISSUE(T + 1);
    const u16* bufA = sA + (T&1)*4096;
    const u16* bufB = sB + (T&1)*4096;
    bf16x8 bfr[4], afr[4];
#pragma unroll
    for (int ni = 0; ni < 4; ni++){
      int r = wc*64 + ni*16 + (l&15);
      int p = (l>>4) ^ ((r>>1)&3);
      bfr[ni] = *(const bf16x8*)&bufB[(r*4 + p)*8];
    }
#pragma unroll
    for (int mi = 0; mi < 4; mi++){
      int r = wr*64 + mi*16 + (l&15);
      int p = (l>>4) ^ ((r>>1)&3);
      afr[mi] = *(const bf16x8*)&bufA[(r*4 + p)*8];
    }
    __builtin_amdgcn_s_setprio(1);
#pragma unroll
    for (int mi = 0; mi < 4; mi++)
#pragma unroll
      for (int ni = 0; ni < 4; ni++)
        acc[mi][ni] = MFMA(afr[mi], bfr[ni], acc[mi][ni]);
    __builtin_amdgcn_s_setprio(0);
  }
  int iLoc = (l>>4)*4, jc = l & 15;
  if (MODE == 0){
    int kind = (nt < 16) ? 0 : (nt < 24) ? 1 : (nt < 32) ? 2 : 3;
#pragma unroll
    for (int ni = 0; ni < 4; ni++){
      int n = nCol0 + wc*64 + ni*16 + jc;
      float bias = (kind == 0) ? bq[n] : (kind == 1) ? bk[n - 2048]
                 : (kind == 2) ? bv[n - 3072] : bg2[n - 4096];
#pragma unroll
      for (int mi = 0; mi < 4; mi++){
        int m = mRow0 + wr*64 + mi*16 + iLoc;
#pragma unroll
        for (int rr = 0; rr < 4; rr++){
          float x = acc[mi][ni][rr] + bias;
          int row = m + rr;
          if (kind == 0)      Cq[(size_t)row*4096 + n] = f2b(fmaxf(x, 0.f) * 0.08838834764831845f);
          else if (kind == 1) Cq[(size_t)row*4096 + n] = f2b(fmaxf(x, 0.f));
          else if (kind == 2) Cq[(size_t)row*4096 + n] = f2b(x);
          else                Cf[(size_t)row*1024 + (n - 4096)] = x;
        }
      }
    }
  } else {
#pragma unroll
    for (int ni = 0; ni < 4; ni++){
      int n = nCol0 + wc*64 + ni*16 + jc;
#pragma unroll
      for (int mi = 0; mi < 4; mi++){
        int m = mRow0 + wr*64 + mi*16 + iLoc;
#pragma unroll
        for (int rr = 0; rr < 4; rr++) Cf[(size_t)(m+rr)*2048 + n] = acc[mi][ni][rr];
      }
    }
  }
}

// ---------------- phase A: logsigmoid, cumsum, eb, kd, T^T = v^T @ kend ----------------
__global__ __launch_bounds__(256) void k_phaseA(const float* __restrict__ g, const u16* __restrict__ QKV,
                                                u16* __restrict__ eb, u16* __restrict__ kd,
                                                u16* __restrict__ T, float* __restrict__ Dv){
  __shared__ float gb[64*128];
  __shared__ u16 keT[128*72];
  __shared__ u16 vT [128*72];
  int c = blockIdx.x, kvh = blockIdx.y, b = blockIdx.z;
  int t = threadIdx.x;
  int tok0 = b*2048 + c*64;
#pragma unroll
  for (int r = 0; r < 8; r++){
    int idx4 = r*256 + t;
    int i = idx4 >> 5, c4 = idx4 & 31;
    float4 v = *(const float4*)&g[(size_t)(tok0+i)*1024 + kvh*128 + c4*4];
    float4 o;
    o.x = (fminf(v.x,0.f) - log1pf(expf(-fabsf(v.x)))) * 0.0625f;
    o.y = (fminf(v.y,0.f) - log1pf(expf(-fabsf(v.y)))) * 0.0625f;
    o.z = (fminf(v.z,0.f) - log1pf(expf(-fabsf(v.z)))) * 0.0625f;
    o.w = (fminf(v.w,0.f) - log1pf(expf(-fabsf(v.w)))) * 0.0625f;
    ((float4*)gb)[i*32 + c4] = o;
  }
  __syncthreads();
  if (t < 128){
    float run = 0.f;
#pragma unroll
    for (int i = 0; i < 64; i++){ run += gb[i*128 + t]; gb[i*128 + t] = run; }
    Dv[((size_t)(b*8+kvh)*32 + c)*128 + t] = expf(run);
  }
  __syncthreads();
  int d0 = (t&15)*8;
  float blast[8];
#pragma unroll
  for (int j = 0; j < 8; j++) blast[j] = gb[63*128 + d0 + j];
#pragma unroll
  for (int r = 0; r < 4; r++){
    int i = (t>>4) + r*16;
    u16x8 kv_ = *(const u16x8*)&QKV[(size_t)(tok0+i)*4096 + 2048 + kvh*128 + d0];
    u16x8 vv  = *(const u16x8*)&QKV[(size_t)(tok0+i)*4096 + 3072 + kvh*128 + d0];
    u16x8 ebv, kdv;
#pragma unroll
    for (int j = 0; j < 8; j++){
      float bcur = gb[i*128 + d0 + j];
      float kf = b2f(kv_[j]);
      ebv[j] = f2b(expf(bcur));
      kdv[j] = f2b(kf * expf(-bcur));
      keT[(d0+j)*72 + i] = f2b(kf * expf(blast[j] - bcur));
      vT [(d0+j)*72 + i] = vv[j];
    }
    *(u16x8*)&eb[(size_t)(tok0+i)*1024 + kvh*128 + d0] = ebv;
    *(u16x8*)&kd[(size_t)(tok0+i)*1024 + kvh*128 + d0] = kdv;
  }
  __syncthreads();
  int w = t>>6, l = t&63;
  f32x4 acc[2][8] = {};
#pragma unroll
  for (int ks = 0; ks < 2; ks++){
    bf16x8 af[2];
#pragma unroll
    for (int te = 0; te < 2; te++)
      af[te] = *(const bf16x8*)&vT[(w*32 + te*16 + (l&15))*72 + ks*32 + (l>>4)*8];
#pragma unroll
    for (int td = 0; td < 8; td++){
      bf16x8 bf_ = *(const bf16x8*)&keT[(td*16 + (l&15))*72 + ks*32 + (l>>4)*8];
#pragma unroll
      for (int te = 0; te < 2; te++) acc[te][td] = MFMA(af[te], bf_, acc[te][td]);
    }
  }
  size_t tbase = ((size_t)(b*8+kvh)*32 + c)*16384;
#pragma unroll
  for (int te = 0; te < 2; te++)
#pragma unroll
    for (int td = 0; td < 8; td++)
#pragma unroll
      for (int rr = 0; rr < 4; rr++){
        int e = w*32 + te*16 + (l>>4)*4 + rr, d = td*16 + (l&15);
        T[tbase + e*128 + d] = f2b(acc[te][td][rr]);
      }
}

// ---------------- phase B: elementwise scan (no LDS, no barriers) ----------------
__global__ __launch_bounds__(256) void k_phaseB(const u16* __restrict__ T, const float* __restrict__ Dv,
                                                u16* __restrict__ SP){
  int kvh = blockIdx.y, b = blockIdx.z;
  int t = threadIdx.x;
  int e = blockIdx.x*16 + (t >> 4);
  int d0 = (t & 15)*8;
  size_t base = ((size_t)(b*8 + kvh)*32)*16384 + (size_t)e*128 + d0;
  size_t dvb  = ((size_t)(b*8 + kvh)*32)*128 + d0;
  float S[8] = {0,0,0,0,0,0,0,0};
#pragma unroll 4
  for (int c = 0; c < 32; c++){
    u16x8 tv = *(const u16x8*)&T[base + (size_t)c*16384];
    float4 dva = *(const float4*)&Dv[dvb + (size_t)c*128];
    float4 dvbv = *(const float4*)&Dv[dvb + (size_t)c*128 + 4];
    u16x8 o;
#pragma unroll
    for (int j = 0; j < 8; j++) o[j] = f2b(S[j]);
    *(u16x8*)&SP[base + (size_t)c*16384] = o;
    float dv[8] = {dva.x, dva.y, dva.z, dva.w, dvbv.x, dvbv.y, dvbv.z, dvbv.w};
#pragma unroll
    for (int j = 0; j < 8; j++) S[j] = S[j]*dv[j] + b2f(tv[j]);
  }
}

// ---------------- phase C: both heads per kv-head (shared kl/vT staging) ----------------
__global__ __launch_bounds__(256) void k_phaseC(const u16* __restrict__ QKV, const u16* __restrict__ eb,
                                                const u16* __restrict__ kd, const u16* __restrict__ SP,
                                                const float* __restrict__ gnw, u16* __restrict__ onrm){
  __shared__ u16 kl[64*128];
  __shared__ u16 sl[64*72];
  __shared__ u16 vT[128*72];
  int c = blockIdx.x, kvh = blockIdx.y, b = blockIdx.z;
  int t = threadIdx.x, w = t>>6, l = t&63;
  int tok0 = b*2048 + c*64;
#pragma unroll
  for (int is = 0; is < 4; is++){
    int row = (t>>4) + is*16;
    int d0s = 8*((t&15) ^ (row&7));
    gload16(&kd[(size_t)(tok0+row)*1024 + kvh*128 + d0s], &kl[is*2048 + w*512]);
  }
  int d0v = (t&15)*8;
#pragma unroll
  for (int r = 0; r < 4; r++){
    int i = (t>>4) + r*16;
    u16x8 vv = *(const u16x8*)&QKV[(size_t)(tok0+i)*4096 + 3072 + kvh*128 + d0v];
#pragma unroll
    for (int jj = 0; jj < 8; jj++) vT[(d0v+jj)*72 + i] = vv[jj];
  }
  // eb fragments (shared between both heads)
  u16x8 evv[4];
  {
    int i = w*16 + (l&15);
#pragma unroll
    for (int kt = 0; kt < 4; kt++){
      int dq = kt*32 + (l>>4)*8;
      evv[kt] = *(const u16x8*)&eb[(size_t)(tok0+i)*1024 + kvh*128 + dq];
    }
  }
  float gw[8];
#pragma unroll
  for (int et = 0; et < 8; et++) gw[et] = gnw[et*16 + (l&15)];
  size_t spb = ((size_t)(b*8+kvh)*32 + c)*16384;
  __syncthreads();
  for (int h2 = 0; h2 < 2; h2++){
    int h = kvh*2 + h2;
    bf16x8 aq[4];
    {
      int i = w*16 + (l&15);
#pragma unroll
      for (int kt = 0; kt < 4; kt++){
        int dq = kt*32 + (l>>4)*8;
        u16x8 qv = *(const u16x8*)&QKV[(size_t)(tok0+i)*4096 + h*128 + dq];
        u16x8 o;
#pragma unroll
        for (int jj = 0; jj < 8; jj++) o[jj] = f2b(b2f(qv[jj]) * b2f(evv[kt][jj]));
        aq[kt] = __builtin_bit_cast(bf16x8, o);
      }
    }
    f32x4 accs[4] = {};
#pragma unroll
    for (int kt = 0; kt < 4; kt++){
#pragma unroll
      for (int jt = 0; jt < 4; jt++){
        int j = jt*16 + (l&15);
        int byte_ = j*256 + ((2*(kt*32 + (l>>4)*8)) ^ ((j&7)<<4));
        bf16x8 bk_ = *(const bf16x8*)((const char*)kl + byte_);
        accs[jt] = MFMA(aq[kt], bk_, accs[jt]);
      }
    }
#pragma unroll
    for (int jt = 0; jt < 4; jt++)
#pragma unroll
      for (int rr = 0; rr < 4; rr++){
        int i = w*16 + (l>>4)*4 + rr;
        int j = jt*16 + (l&15);
        sl[i*72 + j] = f2b((i >= j) ? accs[jt][rr] : 0.f);
      }
    f32x4 acco[8] = {};
#pragma unroll
    for (int kt = 0; kt < 4; kt++){
#pragma unroll
      for (int et = 0; et < 8; et++){
        int e = et*16 + (l&15);
        int dd = kt*32 + (l>>4)*8;
        bf16x8 bs = *(const bf16x8*)&SP[spb + (size_t)e*128 + dd];
        acco[et] = MFMA(aq[kt], bs, acco[et]);
      }
    }
    __syncthreads();
#pragma unroll
    for (int kt2 = 0; kt2 < 2; kt2++){
      int i = w*16 + (l&15);
      bf16x8 as = *(const bf16x8*)&sl[i*72 + kt2*32 + (l>>4)*8];
#pragma unroll
      for (int et = 0; et < 8; et++){
        bf16x8 bv_ = *(const bf16x8*)&vT[(et*16 + (l&15))*72 + kt2*32 + (l>>4)*8];
        acco[et] = MFMA(as, bv_, acco[et]);
      }
    }
#pragma unroll
    for (int rr = 0; rr < 4; rr++){
      int i = w*16 + (l>>4)*4 + rr;
      float ss = 0.f;
#pragma unroll
      for (int et = 0; et < 8; et++){ float x = acco[et][rr]; ss += x*x; }
      ss += __shfl_xor(ss, 1); ss += __shfl_xor(ss, 2);
      ss += __shfl_xor(ss, 4); ss += __shfl_xor(ss, 8);
      float sc = rsqrtf(ss*(1.f/128.f) + 1e-5f);
#pragma unroll
      for (int et = 0; et < 8; et++){
        int e = et*16 + (l&15);
        onrm[(size_t)(tok0+i)*2048 + h*128 + e] = f2b(acco[et][rr]*sc*gw[et]);
      }
    }
    __syncthreads();   // sl reuse guard for next head
  }
}

extern "C" void kernel_launch(void* const* d_in, const int* in_sizes, int n_in,
                              void* d_out, int out_size, void* d_ws, size_t ws_size,
                              hipStream_t stream){
  (void)in_sizes; (void)n_in; (void)out_size; (void)ws_size;
  const float* h   = (const float*)d_in[0];
  const float* Wq  = (const float*)d_in[1];
  const float* bq  = (const float*)d_in[2];
  const float* Wk  = (const float*)d_in[3];
  const float* bk  = (const float*)d_in[4];
  const float* Wv  = (const float*)d_in[5];
  const float* bv  = (const float*)d_in[6];
  const float* Wg1 = (const float*)d_in[7];
  const float* Wg2 = (const float*)d_in[8];
  const float* bg2 = (const float*)d_in[9];
  const float* gnw = (const float*)d_in[10];
  const float* Wo  = (const float*)d_in[11];
  float* out = (float*)d_out;
  char* ws = (char*)d_ws;
  u16*   hb   = (u16*)  (ws + OFF_HB);
  u16*   wct  = (u16*)  (ws + OFF_WCT);
  u16*   wot  = (u16*)  (ws + OFF_WOT);
  u16*   qkv  = (u16*)  (ws + OFF_QKV);
  float* gbuf = (float*)(ws + OFF_G);
  u16*   ebuf = (u16*)  (ws + OFF_EB);
  u16*   kdb  = (u16*)  (ws + OFF_KD);
  u16*   Tb   = (u16*)  (ws + OFF_T);
  float* Dvb  = (float*)(ws + OFF_DV);
  u16*   SPb  = (u16*)  (ws + OFF_SP);
  u16*   onb  = (u16*)  (ws + OFF_ON);
  u16*   wtilT= (u16*)  (ws + OFF_WTL);

  k_prep<<<5248, 256, 0, stream>>>(h, hb, Wq, Wk, Wv, Wo, wct, wot, Wg1, Wg2, wtilT);
  gemm128<0><<<1280, 256, 0, stream>>>(hb, wct, wtilT, qkv, gbuf, bq, bk, bv, bg2);
  k_phaseA<<<dim3(32,8,2), 256, 0, stream>>>(gbuf, qkv, ebuf, kdb, Tb, Dvb);
  k_phaseB<<<dim3(8,8,2), 256, 0, stream>>>(Tb, Dvb, SPb);
  k_phaseC<<<dim3(32,8,2), 256, 0, stream>>>(qkv, ebuf, kdb, SPb, gnw, onb);
  gemm128<1><<<512, 256, 0, stream>>>(onb, wot, nullptr, nullptr, out, nullptr, nullptr, nullptr, nullptr);
}